// Round 2
// baseline (766.858 us; speedup 1.0000x reference)
//
#include <hip/hip_runtime.h>

#define B_  2
#define T_  2048
#define H_  1024
#define NH_ 16
#define HD_ 64
#define M_  (B_*T_)   // 4096 rows
#define AS_ 72        // attention LDS row stride (64 data + 8 pad)

typedef __bf16 bf16x8 __attribute__((ext_vector_type(8)));
typedef float  floatx4 __attribute__((ext_vector_type(4)));

// ---------------------------------------------------------------- transpose
// in: fp32 [K][N] row-major  ->  out: bf16 [N][K] row-major
__global__ __launch_bounds__(256) void transpose_bf16(
    const float* __restrict__ in, __bf16* __restrict__ out, int K, int N)
{
    __shared__ float tile[32][33];
    const int k0 = blockIdx.x * 32, n0 = blockIdx.y * 32;
    const int tx = threadIdx.x & 31, ty = threadIdx.x >> 5;   // ty 0..7
#pragma unroll
    for (int i = 0; i < 32; i += 8)
        tile[ty + i][tx] = in[(size_t)(k0 + ty + i) * N + (n0 + tx)];
    __syncthreads();
#pragma unroll
    for (int i = 0; i < 32; i += 8)
        out[(size_t)(n0 + ty + i) * K + (k0 + tx)] = (__bf16)tile[tx][ty + i];
}

// ---------------------------------------------------------------- group norm
// x fp32 [B,T,H]; normalize over (T, 32ch) per (b,g); out bf16 [B*T][H]
__global__ __launch_bounds__(256) void groupnorm_bf16(
    const float* __restrict__ x, const float* __restrict__ w,
    const float* __restrict__ bsc, __bf16* __restrict__ out)
{
    const int bg = blockIdx.x, batch = bg >> 5, g = bg & 31;
    const float* xp = x + (size_t)batch * T_ * H_ + g * 32;
    float s = 0.f, ss = 0.f;
    for (int i = threadIdx.x; i < T_ * 32; i += 256) {
        const int t = i >> 5, c = i & 31;
        const float v = xp[(size_t)t * H_ + c];
        s += v; ss += v * v;
    }
#pragma unroll
    for (int off = 32; off > 0; off >>= 1) {
        s  += __shfl_down(s,  off, 64);
        ss += __shfl_down(ss, off, 64);
    }
    __shared__ float rs[4], rss[4];
    const int wv = threadIdx.x >> 6, lane = threadIdx.x & 63;
    if (lane == 0) { rs[wv] = s; rss[wv] = ss; }
    __syncthreads();
    const float S  = rs[0] + rs[1] + rs[2] + rs[3];
    const float SS = rss[0] + rss[1] + rss[2] + rss[3];
    const float inv = 1.f / (float)(T_ * 32);
    const float mean = S * inv;
    const float var  = SS * inv - mean * mean;
    const float rstd = rsqrtf(var + 1e-5f);
    for (int i = threadIdx.x; i < T_ * 32; i += 256) {
        const int t = i >> 5, c = i & 31, h = g * 32 + c;
        const float v = xp[(size_t)t * H_ + c];
        out[((size_t)(batch * T_ + t)) * H_ + h] =
            (__bf16)(((v - mean) * rstd) * w[h] + bsc[h]);
    }
}

// ---------------------------------------------------------------- GEMM core
// C[128x128] per block, 4 waves each 64x64 (4x4 of 16x16x32 mfma).
// A bf16 [M][K] row-major; BT bf16 [N][K] row-major. LDS rows padded to 40.
__device__ __forceinline__ void gemm_core(
    const __bf16* __restrict__ A, const __bf16* __restrict__ BT,
    int K, int m0, int n0, __bf16* As, __bf16* Bs, floatx4 (&acc)[4][4])
{
    const int tid  = threadIdx.x;
    const int lane = tid & 63, wv = tid >> 6;
    const int quad = lane >> 4, l16 = lane & 15;
    const int wm = (wv >> 1) * 64, wn = (wv & 1) * 64;
    const int r0 = tid >> 2, cc0 = (tid & 3) * 8;     // 512 chunks of 8 bf16

    const __bf16* Ag0 = A  + (size_t)(m0 + r0)      * K + cc0;
    const __bf16* Ag1 = A  + (size_t)(m0 + r0 + 64) * K + cc0;
    const __bf16* Bg0 = BT + (size_t)(n0 + r0)      * K + cc0;
    const __bf16* Bg1 = BT + (size_t)(n0 + r0 + 64) * K + cc0;
    __bf16* as0 = As + r0 * 40 + cc0;
    __bf16* as1 = As + (r0 + 64) * 40 + cc0;
    __bf16* bs0 = Bs + r0 * 40 + cc0;
    __bf16* bs1 = Bs + (r0 + 64) * 40 + cc0;

    for (int kt = 0; kt < K; kt += 32) {
        const uint4 va0 = *(const uint4*)(Ag0 + kt);
        const uint4 va1 = *(const uint4*)(Ag1 + kt);
        const uint4 vb0 = *(const uint4*)(Bg0 + kt);
        const uint4 vb1 = *(const uint4*)(Bg1 + kt);
        __syncthreads();                 // previous iter's LDS reads done
        *(uint4*)as0 = va0;  *(uint4*)as1 = va1;
        *(uint4*)bs0 = vb0;  *(uint4*)bs1 = vb1;
        __syncthreads();
        bf16x8 af[4], bfg[4];
#pragma unroll
        for (int i = 0; i < 4; ++i)
            af[i]  = *(const bf16x8*)(As + (wm + i * 16 + l16) * 40 + quad * 8);
#pragma unroll
        for (int i = 0; i < 4; ++i)
            bfg[i] = *(const bf16x8*)(Bs + (wn + i * 16 + l16) * 40 + quad * 8);
#pragma unroll
        for (int mi = 0; mi < 4; ++mi)
#pragma unroll
            for (int ni = 0; ni < 4; ++ni)
                acc[mi][ni] = __builtin_amdgcn_mfma_f32_16x16x32_bf16(
                    af[mi], bfg[ni], acc[mi][ni], 0, 0, 0);
    }
}

#define GEMM_PROLOGUE(KVAL)                                             \
    __shared__ __align__(16) __bf16 As[128 * 40], Bs[128 * 40];         \
    const int m0 = blockIdx.x * 128, n0 = blockIdx.y * 128;             \
    floatx4 acc[4][4];                                                  \
    { floatx4 z = {0.f, 0.f, 0.f, 0.f};                                 \
      for (int i = 0; i < 4; ++i) for (int j = 0; j < 4; ++j) acc[i][j] = z; } \
    gemm_core(A, BT, (KVAL), m0, n0, As, Bs, acc);                      \
    const int tid = threadIdx.x, lane = tid & 63, wv = tid >> 6;        \
    const int quad = lane >> 4, l16 = lane & 15;                        \
    const int wm = (wv >> 1) * 64, wn = (wv & 1) * 64;                  \
    (void)tid;

// QKV: scatter to q/k/v bf16 [B,NH,T,HD] + present fp32 [2,B,NH,T,HD]
__global__ __launch_bounds__(256) void gemm_qkv(
    const __bf16* __restrict__ A, const __bf16* __restrict__ BT,
    const float* __restrict__ bias, __bf16* __restrict__ qb,
    __bf16* __restrict__ kb, __bf16* __restrict__ vb,
    float* __restrict__ present)
{
    GEMM_PROLOGUE(H_)
#pragma unroll
    for (int ni = 0; ni < 4; ++ni) {
        const int col = n0 + wn + ni * 16 + l16;
        const float bv = bias[col];
        const int which = col >> 10, c = col & 1023, hh = c >> 6, d = c & 63;
#pragma unroll
        for (int mi = 0; mi < 4; ++mi)
#pragma unroll
            for (int r = 0; r < 4; ++r) {
                const int row = m0 + wm + mi * 16 + quad * 4 + r;
                const int bb = row >> 11, t = row & 2047;
                const float v = acc[mi][ni][r] + bv;
                const size_t idx = (((size_t)bb * NH_ + hh) * T_ + t) * HD_ + d;
                if (which == 0)      qb[idx] = (__bf16)v;
                else if (which == 1) { kb[idx] = (__bf16)v; present[idx] = v; }
                else { vb[idx] = (__bf16)v;
                       present[(size_t)B_ * NH_ * T_ * HD_ + idx] = v; }
            }
    }
}

// out fp32 [M][N] = acc + bias + resid   (aproj and mproj epilogues)
__global__ __launch_bounds__(256) void gemm_resid(
    const __bf16* __restrict__ A, const __bf16* __restrict__ BT,
    const float* __restrict__ bias, const float* __restrict__ resid,
    float* __restrict__ out, int K, int N)
{
    GEMM_PROLOGUE(K)
#pragma unroll
    for (int ni = 0; ni < 4; ++ni) {
        const int col = n0 + wn + ni * 16 + l16;
        const float bv = bias[col];
#pragma unroll
        for (int mi = 0; mi < 4; ++mi)
#pragma unroll
            for (int r = 0; r < 4; ++r) {
                const int row = m0 + wm + mi * 16 + quad * 4 + r;
                const size_t idx = (size_t)row * N + col;
                out[idx] = acc[mi][ni][r] + bv + resid[idx];
            }
    }
}

// out bf16 [M][4H] = gelu(acc + bias)
__global__ __launch_bounds__(256) void gemm_gelu(
    const __bf16* __restrict__ A, const __bf16* __restrict__ BT,
    const float* __restrict__ bias, __bf16* __restrict__ out)
{
    GEMM_PROLOGUE(H_)
#pragma unroll
    for (int ni = 0; ni < 4; ++ni) {
        const int col = n0 + wn + ni * 16 + l16;
        const float bv = bias[col];
#pragma unroll
        for (int mi = 0; mi < 4; ++mi)
#pragma unroll
            for (int r = 0; r < 4; ++r) {
                const int row = m0 + wm + mi * 16 + quad * 4 + r;
                const float v = acc[mi][ni][r] + bv;
                const float g = 0.5f * v *
                    (1.f + tanhf(0.7978845608028654f * (v + 0.044715f * v * v * v)));
                out[(size_t)row * (4 * H_) + col] = (__bf16)g;
            }
    }
}

// ---------------------------------------------------------------- attention
// flash-style: block = (qtile of 64 rows, bh). 4 waves; wave owns 16 q rows.
// q,k,v bf16 [B,NH,T,HD]; out bf16 [B*T][H] (token-major for aproj GEMM).
__global__ __launch_bounds__(256) void attn_kernel(
    const __bf16* __restrict__ qb, const __bf16* __restrict__ kb,
    const __bf16* __restrict__ vb, __bf16* __restrict__ aout)
{
    const int qt = blockIdx.x, bh = blockIdx.y;
    const int bb = bh >> 4, hh = bh & 15;
    const __bf16* Q  = qb + (size_t)bh * T_ * HD_;
    const __bf16* Kp = kb + (size_t)bh * T_ * HD_;
    const __bf16* Vp = vb + (size_t)bh * T_ * HD_;
    __shared__ __align__(16) __bf16 Qs[64 * AS_], Ks[64 * AS_],
                                    Vts[64 * AS_], Ps[64 * AS_];

    const int tid = threadIdx.x, lane = tid & 63, wv = tid >> 6;
    const int quad = lane >> 4, l16 = lane & 15;

    // stage Q tile [64 rows][64 d]
#pragma unroll
    for (int c = tid; c < 512; c += 256) {
        const int r = c >> 3, cc = (c & 7) * 8;
        *(uint4*)(Qs + r * AS_ + cc) =
            *(const uint4*)(Q + ((size_t)(qt * 64 + r)) * HD_ + cc);
    }

    float m_i[4], l_i[4];
    floatx4 Ov[4];
    {
        floatx4 z = {0.f, 0.f, 0.f, 0.f};
#pragma unroll
        for (int i = 0; i < 4; ++i) { Ov[i] = z; m_i[i] = -1e30f; l_i[i] = 0.f; }
    }

    for (int kt = 0; kt <= qt; ++kt) {
        __syncthreads();   // prior iter's LDS reads (and Q writes) complete
#pragma unroll
        for (int c = tid; c < 512; c += 256) {
            const int r = c >> 3, cc = (c & 7) * 8;
            *(uint4*)(Ks + r * AS_ + cc) =
                *(const uint4*)(Kp + ((size_t)(kt * 64 + r)) * HD_ + cc);
            uint4 vv = *(const uint4*)(Vp + ((size_t)(kt * 64 + r)) * HD_ + cc);
            const __bf16* pv = (const __bf16*)&vv;
#pragma unroll
            for (int j = 0; j < 8; ++j) Vts[(cc + j) * AS_ + r] = pv[j];  // V^T
        }
        __syncthreads();

        // S = Q K^T for this wave's 16 rows
        floatx4 sacc[4];
        { floatx4 z = {0.f, 0.f, 0.f, 0.f};
          for (int i = 0; i < 4; ++i) sacc[i] = z; }
#pragma unroll
        for (int kk = 0; kk < 2; ++kk) {
            const bf16x8 aq = *(const bf16x8*)(Qs + (wv * 16 + l16) * AS_ + kk * 32 + quad * 8);
#pragma unroll
            for (int ni = 0; ni < 4; ++ni) {
                const bf16x8 bk = *(const bf16x8*)(Ks + (ni * 16 + l16) * AS_ + kk * 32 + quad * 8);
                sacc[ni] = __builtin_amdgcn_mfma_f32_16x16x32_bf16(aq, bk, sacc[ni], 0, 0, 0);
            }
        }
        // causal mask on the diagonal tile
        if (kt == qt) {
#pragma unroll
            for (int ni = 0; ni < 4; ++ni) {
                const int colL = ni * 16 + l16;
#pragma unroll
                for (int r = 0; r < 4; ++r)
                    if (colL > wv * 16 + quad * 4 + r) sacc[ni][r] = -1e30f;
            }
        }
        // online softmax: rows quad*4+r, cols spread over the 16-lane group
        float rmax[4];
#pragma unroll
        for (int r = 0; r < 4; ++r)
            rmax[r] = fmaxf(fmaxf(sacc[0][r], sacc[1][r]),
                            fmaxf(sacc[2][r], sacc[3][r]));
#pragma unroll
        for (int off = 1; off < 16; off <<= 1)
#pragma unroll
            for (int r = 0; r < 4; ++r)
                rmax[r] = fmaxf(rmax[r], __shfl_xor(rmax[r], off, 64));
        float alpha[4], rsum[4];
#pragma unroll
        for (int r = 0; r < 4; ++r) {
            const float mn = fmaxf(m_i[r], rmax[r]);
            alpha[r] = __expf(m_i[r] - mn);
            m_i[r] = mn;
            rsum[r] = 0.f;
        }
#pragma unroll
        for (int ni = 0; ni < 4; ++ni)
#pragma unroll
            for (int r = 0; r < 4; ++r) {
                const float p = __expf(sacc[ni][r] - m_i[r]);
                sacc[ni][r] = p;
                rsum[r] += p;
            }
#pragma unroll
        for (int off = 1; off < 16; off <<= 1)
#pragma unroll
            for (int r = 0; r < 4; ++r)
                rsum[r] += __shfl_xor(rsum[r], off, 64);
#pragma unroll
        for (int r = 0; r < 4; ++r) l_i[r] = l_i[r] * alpha[r] + rsum[r];
#pragma unroll
        for (int ni = 0; ni < 4; ++ni)
#pragma unroll
            for (int r = 0; r < 4; ++r) Ov[ni][r] *= alpha[r];

        // P: C-layout -> A-layout via LDS (wave-private region)
#pragma unroll
        for (int ni = 0; ni < 4; ++ni)
#pragma unroll
            for (int r = 0; r < 4; ++r)
                Ps[(wv * 16 + quad * 4 + r) * AS_ + ni * 16 + l16] = (__bf16)sacc[ni][r];
        __syncthreads();
        // O += P V
#pragma unroll
        for (int kk = 0; kk < 2; ++kk) {
            const bf16x8 ap = *(const bf16x8*)(Ps + (wv * 16 + l16) * AS_ + kk * 32 + quad * 8);
#pragma unroll
            for (int ni = 0; ni < 4; ++ni) {
                const bf16x8 bv2 = *(const bf16x8*)(Vts + (ni * 16 + l16) * AS_ + kk * 32 + quad * 8);
                Ov[ni] = __builtin_amdgcn_mfma_f32_16x16x32_bf16(ap, bv2, Ov[ni], 0, 0, 0);
            }
        }
    }
    // epilogue: aout[(b*T + t)][h*64 + d] = O / l
#pragma unroll
    for (int ni = 0; ni < 4; ++ni)
#pragma unroll
        for (int r = 0; r < 4; ++r) {
            const int t = qt * 64 + wv * 16 + quad * 4 + r;
            aout[((size_t)(bb * T_ + t)) * H_ + hh * HD_ + ni * 16 + l16] =
                (__bf16)(Ov[ni][r] / l_i[r]);
        }
}

// ---------------------------------------------------------------- launch
extern "C" void kernel_launch(void* const* d_in, const int* in_sizes, int n_in,
                              void* d_out, int out_size, void* d_ws, size_t ws_size,
                              hipStream_t stream)
{
    (void)in_sizes; (void)n_in; (void)out_size; (void)ws_size;
    const float* x       = (const float*)d_in[0];
    const float* w_attn  = (const float*)d_in[1];
    const float* b_attn  = (const float*)d_in[2];
    const float* w_aproj = (const float*)d_in[3];
    const float* b_aproj = (const float*)d_in[4];
    const float* ln1_w   = (const float*)d_in[5];
    const float* ln1_b   = (const float*)d_in[6];
    const float* ln2_w   = (const float*)d_in[7];
    const float* ln2_b   = (const float*)d_in[8];
    const float* w_fc    = (const float*)d_in[9];
    const float* b_fc    = (const float*)d_in[10];
    const float* w_mproj = (const float*)d_in[11];
    const float* b_mproj = (const float*)d_in[12];
    float* out = (float*)d_out;
    float* present = out + (size_t)M_ * H_;

    char* wp = (char*)d_ws;
    auto alloc = [&](size_t bytes) {
        void* p = (void*)wp; wp += (bytes + 255) & ~(size_t)255; return p;
    };
    __bf16* A1       = (__bf16*)alloc((size_t)M_ * H_ * 2);
    __bf16* A2       = (__bf16*)alloc((size_t)M_ * H_ * 2);
    __bf16* WattnT   = (__bf16*)alloc((size_t)3 * H_ * H_ * 2);
    __bf16* WaprojT  = (__bf16*)alloc((size_t)H_ * H_ * 2);
    __bf16* WfcT     = (__bf16*)alloc((size_t)4 * H_ * H_ * 2);
    __bf16* WmprojT  = (__bf16*)alloc((size_t)4 * H_ * H_ * 2);
    __bf16* qb       = (__bf16*)alloc((size_t)M_ * H_ * 2);
    __bf16* kb       = (__bf16*)alloc((size_t)M_ * H_ * 2);
    __bf16* vbuf     = (__bf16*)alloc((size_t)M_ * H_ * 2);
    __bf16* attn_out = (__bf16*)alloc((size_t)M_ * H_ * 2);
    float*  x2       = (float*) alloc((size_t)M_ * H_ * 4);
    __bf16* Hbuf     = (__bf16*)alloc((size_t)M_ * 4 * H_ * 2);

    transpose_bf16<<<dim3(H_/32, 3*H_/32), 256, 0, stream>>>(w_attn,  WattnT,  H_,   3*H_);
    transpose_bf16<<<dim3(H_/32, H_/32),   256, 0, stream>>>(w_aproj, WaprojT, H_,   H_);
    transpose_bf16<<<dim3(H_/32, 4*H_/32), 256, 0, stream>>>(w_fc,    WfcT,    H_,   4*H_);
    transpose_bf16<<<dim3(4*H_/32, H_/32), 256, 0, stream>>>(w_mproj, WmprojT, 4*H_, H_);

    groupnorm_bf16<<<64, 256, 0, stream>>>(x, ln1_w, ln1_b, A1);
    gemm_qkv<<<dim3(M_/128, 3*H_/128), 256, 0, stream>>>(A1, WattnT, b_attn,
                                                         qb, kb, vbuf, present);
    attn_kernel<<<dim3(T_/64, B_*NH_), 256, 0, stream>>>(qb, kb, vbuf, attn_out);
    gemm_resid<<<dim3(M_/128, H_/128), 256, 0, stream>>>(attn_out, WaprojT, b_aproj,
                                                         x, x2, H_, H_);
    groupnorm_bf16<<<64, 256, 0, stream>>>(x2, ln2_w, ln2_b, A2);
    gemm_gelu<<<dim3(M_/128, 4*H_/128), 256, 0, stream>>>(A2, WfcT, b_fc, Hbuf);
    gemm_resid<<<dim3(M_/128, H_/128), 256, 0, stream>>>(Hbuf, WmprojT, b_mproj,
                                                         x2, out, 4*H_, H_);
}

// Round 3
// 677.830 us; speedup vs baseline: 1.1313x; 1.1313x over previous
//
#include <hip/hip_runtime.h>

#define B_  2
#define T_  2048
#define H_  1024
#define NH_ 16
#define HD_ 64
#define M_  (B_*T_)   // 4096 rows
#define AS_ 72        // attention LDS row stride (64 data + 8 pad)

typedef __bf16 bf16x8 __attribute__((ext_vector_type(8)));
typedef float  floatx4 __attribute__((ext_vector_type(4)));

typedef __attribute__((address_space(1))) const unsigned int gas_u32;
typedef __attribute__((address_space(3))) unsigned int       las_u32;

__device__ __forceinline__ void gload_lds16(const __bf16* g, __bf16* l) {
    __builtin_amdgcn_global_load_lds((gas_u32*)g, (las_u32*)l, 16, 0, 0);
}

// ---------------------------------------------------------------- transpose
__global__ __launch_bounds__(256) void transpose_bf16(
    const float* __restrict__ in, __bf16* __restrict__ out, int K, int N)
{
    __shared__ float tile[32][33];
    const int k0 = blockIdx.x * 32, n0 = blockIdx.y * 32;
    const int tx = threadIdx.x & 31, ty = threadIdx.x >> 5;
#pragma unroll
    for (int i = 0; i < 32; i += 8)
        tile[ty + i][tx] = in[(size_t)(k0 + ty + i) * N + (n0 + tx)];
    __syncthreads();
#pragma unroll
    for (int i = 0; i < 32; i += 8)
        out[(size_t)(n0 + ty + i) * K + (k0 + tx)] = (__bf16)tile[tx][ty + i];
}

// ---------------------------------------------------------------- group norm
__global__ __launch_bounds__(256) void groupnorm_bf16(
    const float* __restrict__ x, const float* __restrict__ w,
    const float* __restrict__ bsc, __bf16* __restrict__ out)
{
    const int bg = blockIdx.x, batch = bg >> 5, g = bg & 31;
    const float* xp = x + (size_t)batch * T_ * H_ + g * 32;
    float s = 0.f, ss = 0.f;
    for (int i = threadIdx.x; i < T_ * 32; i += 256) {
        const int t = i >> 5, c = i & 31;
        const float v = xp[(size_t)t * H_ + c];
        s += v; ss += v * v;
    }
#pragma unroll
    for (int off = 32; off > 0; off >>= 1) {
        s  += __shfl_down(s,  off, 64);
        ss += __shfl_down(ss, off, 64);
    }
    __shared__ float rs[4], rss[4];
    const int wv = threadIdx.x >> 6, lane = threadIdx.x & 63;
    if (lane == 0) { rs[wv] = s; rss[wv] = ss; }
    __syncthreads();
    const float S  = rs[0] + rs[1] + rs[2] + rs[3];
    const float SS = rss[0] + rss[1] + rss[2] + rss[3];
    const float inv = 1.f / (float)(T_ * 32);
    const float mean = S * inv;
    const float var  = SS * inv - mean * mean;
    const float rstd = rsqrtf(var + 1e-5f);
    for (int i = threadIdx.x; i < T_ * 32; i += 256) {
        const int t = i >> 5, c = i & 31, h = g * 32 + c;
        const float v = xp[(size_t)t * H_ + c];
        out[((size_t)(batch * T_ + t)) * H_ + h] =
            (__bf16)(((v - mean) * rstd) * w[h] + bsc[h]);
    }
}

// ---------------------------------------------------------------- GEMM core
// m97 recipe: global_load_lds width 16, LDS unpadded stride 32 (lds = base+tid*16B)
__device__ __forceinline__ void gemm_core(
    const __bf16* __restrict__ A, const __bf16* __restrict__ BT,
    int K, int m0, int n0, __bf16* As, __bf16* Bs, floatx4 (&acc)[4][4])
{
    const int tid  = threadIdx.x;
    const int lane = tid & 63, wv = tid >> 6;
    const int quad = lane >> 4, l16 = lane & 15;
    const int wm = (wv >> 1) * 64, wn = (wv & 1) * 64;
    const int r0 = tid >> 2, cc0 = (tid & 3) * 8;

    const __bf16* Ag0 = A  + (size_t)(m0 + r0)      * K + cc0;
    const __bf16* Ag1 = A  + (size_t)(m0 + r0 + 64) * K + cc0;
    const __bf16* Bg0 = BT + (size_t)(n0 + r0)      * K + cc0;
    const __bf16* Bg1 = BT + (size_t)(n0 + r0 + 64) * K + cc0;
    __bf16* asd0 = As + tid * 8;           // (r0*32+cc0) == tid*8
    __bf16* asd1 = As + 2048 + tid * 8;
    __bf16* bsd0 = Bs + tid * 8;
    __bf16* bsd1 = Bs + 2048 + tid * 8;

    for (int kt = 0; kt < K; kt += 32) {
        __syncthreads();                 // prev iter's LDS reads done
        gload_lds16(Ag0 + kt, asd0);
        gload_lds16(Ag1 + kt, asd1);
        gload_lds16(Bg0 + kt, bsd0);
        gload_lds16(Bg1 + kt, bsd1);
        __syncthreads();                 // drains vmcnt -> LDS filled
        bf16x8 af[4], bfg[4];
#pragma unroll
        for (int i = 0; i < 4; ++i)
            af[i]  = *(const bf16x8*)(As + (wm + i * 16 + l16) * 32 + quad * 8);
#pragma unroll
        for (int i = 0; i < 4; ++i)
            bfg[i] = *(const bf16x8*)(Bs + (wn + i * 16 + l16) * 32 + quad * 8);
#pragma unroll
        for (int mi = 0; mi < 4; ++mi)
#pragma unroll
            for (int ni = 0; ni < 4; ++ni)
                acc[mi][ni] = __builtin_amdgcn_mfma_f32_16x16x32_bf16(
                    af[mi], bfg[ni], acc[mi][ni], 0, 0, 0);
    }
}

#define GEMM_PROLOGUE(KVAL)                                             \
    __shared__ __align__(16) __bf16 As[128 * 32], Bs[128 * 32];         \
    const int m0 = blockIdx.x * 128, n0 = blockIdx.y * 128;             \
    floatx4 acc[4][4];                                                  \
    { floatx4 z = {0.f, 0.f, 0.f, 0.f};                                 \
      for (int i = 0; i < 4; ++i) for (int j = 0; j < 4; ++j) acc[i][j] = z; } \
    gemm_core(A, BT, (KVAL), m0, n0, As, Bs, acc);                      \
    const int tid = threadIdx.x, lane = tid & 63, wv = tid >> 6;        \
    const int quad = lane >> 4, l16 = lane & 15;                        \
    const int wm = (wv >> 1) * 64, wn = (wv & 1) * 64;                  \
    (void)tid;

// QKV: q,k bf16 [B,NH,T,HD]; v transposed bf16 [B,NH,HD,T]; present fp32
__global__ __launch_bounds__(256) void gemm_qkv(
    const __bf16* __restrict__ A, const __bf16* __restrict__ BT,
    const float* __restrict__ bias, __bf16* __restrict__ qb,
    __bf16* __restrict__ kb, __bf16* __restrict__ vtb,
    float* __restrict__ present)
{
    GEMM_PROLOGUE(H_)
#pragma unroll
    for (int ni = 0; ni < 4; ++ni) {
        const int col = n0 + wn + ni * 16 + l16;
        const float bv = bias[col];
        const int which = col >> 10, c = col & 1023, hh = c >> 6, d = c & 63;
#pragma unroll
        for (int mi = 0; mi < 4; ++mi)
#pragma unroll
            for (int r = 0; r < 4; ++r) {
                const int row = m0 + wm + mi * 16 + quad * 4 + r;
                const int bb = row >> 11, t = row & 2047;
                const float v = acc[mi][ni][r] + bv;
                const size_t idx = (((size_t)bb * NH_ + hh) * T_ + t) * HD_ + d;
                if (which == 0)      qb[idx] = (__bf16)v;
                else if (which == 1) { kb[idx] = (__bf16)v; present[idx] = v; }
                else { vtb[(((size_t)bb * NH_ + hh) * HD_ + d) * T_ + t] = (__bf16)v;
                       present[(size_t)B_ * NH_ * T_ * HD_ + idx] = v; }
            }
    }
}

__global__ __launch_bounds__(256) void gemm_resid(
    const __bf16* __restrict__ A, const __bf16* __restrict__ BT,
    const float* __restrict__ bias, const float* __restrict__ resid,
    float* __restrict__ out, int K, int N)
{
    GEMM_PROLOGUE(K)
#pragma unroll
    for (int ni = 0; ni < 4; ++ni) {
        const int col = n0 + wn + ni * 16 + l16;
        const float bv = bias[col];
#pragma unroll
        for (int mi = 0; mi < 4; ++mi)
#pragma unroll
            for (int r = 0; r < 4; ++r) {
                const int row = m0 + wm + mi * 16 + quad * 4 + r;
                const size_t idx = (size_t)row * N + col;
                out[idx] = acc[mi][ni][r] + bv + resid[idx];
            }
    }
}

__global__ __launch_bounds__(256) void gemm_gelu(
    const __bf16* __restrict__ A, const __bf16* __restrict__ BT,
    const float* __restrict__ bias, __bf16* __restrict__ out)
{
    GEMM_PROLOGUE(H_)
#pragma unroll
    for (int ni = 0; ni < 4; ++ni) {
        const int col = n0 + wn + ni * 16 + l16;
        const float bv = bias[col];
#pragma unroll
        for (int mi = 0; mi < 4; ++mi)
#pragma unroll
            for (int r = 0; r < 4; ++r) {
                const int row = m0 + wm + mi * 16 + quad * 4 + r;
                const float v = acc[mi][ni][r] + bv;
                const float g = 0.5f * v *
                    (1.f + tanhf(0.7978845608028654f * (v + 0.044715f * v * v * v)));
                out[(size_t)row * (4 * H_) + col] = (__bf16)g;
            }
    }
}

// ---------------------------------------------------------------- attention
// Balanced pairs: block handles q-supertiles p and 15-p (128 rows each) ->
// exactly 34 k-iterations/block. 4 waves x 32 q-rows. V pre-transposed.
__global__ __launch_bounds__(256) void attn_kernel(
    const __bf16* __restrict__ qb, const __bf16* __restrict__ kb,
    const __bf16* __restrict__ vtb, __bf16* __restrict__ aout)
{
    const int p = blockIdx.x, bh = blockIdx.y;
    const int bb = bh >> 4, hh = bh & 15;
    const __bf16* Q  = qb  + (size_t)bh * T_ * HD_;
    const __bf16* Kp = kb  + (size_t)bh * T_ * HD_;
    const __bf16* VT = vtb + (size_t)bh * HD_ * T_;
    __shared__ __align__(16) __bf16 Qs[128 * AS_], Ks[64 * AS_],
                                    Vts[64 * AS_], Ps[128 * AS_];

    const int tid = threadIdx.x, lane = tid & 63, wv = tid >> 6;
    const int quad = lane >> 4, l16 = lane & 15;
    const int r0 = tid >> 3, cc0 = (tid & 7) * 8;   // staging: 64x64 tiles

    for (int half = 0; half < 2; ++half) {
        const int sp = half ? (15 - p) : p;
        const int q0 = sp * 128;
        const int nkt = 2 * sp + 2;

        __syncthreads();   // prior half's Qs/Ps reads done
#pragma unroll
        for (int c = tid; c < 1024; c += 256) {
            const int r = c >> 3, cc = (c & 7) * 8;
            *(uint4*)(Qs + r * AS_ + cc) =
                *(const uint4*)(Q + (size_t)(q0 + r) * HD_ + cc);
        }

        float m_i[2][4], l_i[2][4];
        floatx4 Ov[2][4];
        {
            floatx4 z = {0.f, 0.f, 0.f, 0.f};
#pragma unroll
            for (int mi = 0; mi < 2; ++mi)
#pragma unroll
                for (int i = 0; i < 4; ++i)
                    { Ov[mi][i] = z; m_i[mi][i] = -1e30f; l_i[mi][i] = 0.f; }
        }

        // prefetch kt=0
        uint4 kr0, kr1, vr0, vr1;
        kr0 = *(const uint4*)(Kp + (size_t)(r0)      * HD_ + cc0);
        kr1 = *(const uint4*)(Kp + (size_t)(r0 + 32) * HD_ + cc0);
        vr0 = *(const uint4*)(VT + (size_t)(r0)      * T_ + cc0);
        vr1 = *(const uint4*)(VT + (size_t)(r0 + 32) * T_ + cc0);

        for (int kt = 0; kt < nkt; ++kt) {
            __syncthreads();   // prev iter's K/V reads done (+ Qs writes for kt=0)
            *(uint4*)(Ks  + r0 * AS_ + cc0)        = kr0;
            *(uint4*)(Ks  + (r0 + 32) * AS_ + cc0) = kr1;
            *(uint4*)(Vts + r0 * AS_ + cc0)        = vr0;
            *(uint4*)(Vts + (r0 + 32) * AS_ + cc0) = vr1;
            __syncthreads();
            if (kt + 1 < nkt) {   // prefetch next tile (overlaps compute)
                const int kn = kt + 1;
                kr0 = *(const uint4*)(Kp + (size_t)(kn * 64 + r0)      * HD_ + cc0);
                kr1 = *(const uint4*)(Kp + (size_t)(kn * 64 + r0 + 32) * HD_ + cc0);
                vr0 = *(const uint4*)(VT + (size_t)(r0)      * T_ + kn * 64 + cc0);
                vr1 = *(const uint4*)(VT + (size_t)(r0 + 32) * T_ + kn * 64 + cc0);
            }

            // S = Q K^T (2 m-tiles x 4 n-tiles per wave)
            floatx4 sacc[2][4];
            { floatx4 z = {0.f, 0.f, 0.f, 0.f};
#pragma unroll
              for (int mi = 0; mi < 2; ++mi)
#pragma unroll
                  for (int i = 0; i < 4; ++i) sacc[mi][i] = z; }
#pragma unroll
            for (int kk = 0; kk < 2; ++kk) {
                bf16x8 aq[2];
#pragma unroll
                for (int mi = 0; mi < 2; ++mi)
                    aq[mi] = *(const bf16x8*)(Qs + (wv * 32 + mi * 16 + l16) * AS_ + kk * 32 + quad * 8);
#pragma unroll
                for (int ni = 0; ni < 4; ++ni) {
                    const bf16x8 bk = *(const bf16x8*)(Ks + (ni * 16 + l16) * AS_ + kk * 32 + quad * 8);
#pragma unroll
                    for (int mi = 0; mi < 2; ++mi)
                        sacc[mi][ni] = __builtin_amdgcn_mfma_f32_16x16x32_bf16(
                            aq[mi], bk, sacc[mi][ni], 0, 0, 0);
                }
            }
            if (kt >= 2 * sp) {    // diagonal supertile: causal mask
#pragma unroll
                for (int mi = 0; mi < 2; ++mi)
#pragma unroll
                    for (int ni = 0; ni < 4; ++ni) {
                        const int key = kt * 64 + ni * 16 + l16;
#pragma unroll
                        for (int r = 0; r < 4; ++r)
                            if (key > q0 + wv * 32 + mi * 16 + quad * 4 + r)
                                sacc[mi][ni][r] = -1e30f;
                    }
            }
            // online softmax (8 rows/lane)
#pragma unroll
            for (int mi = 0; mi < 2; ++mi) {
                float rmax[4], alpha[4], rsum[4];
#pragma unroll
                for (int r = 0; r < 4; ++r)
                    rmax[r] = fmaxf(fmaxf(sacc[mi][0][r], sacc[mi][1][r]),
                                    fmaxf(sacc[mi][2][r], sacc[mi][3][r]));
#pragma unroll
                for (int off = 1; off < 16; off <<= 1)
#pragma unroll
                    for (int r = 0; r < 4; ++r)
                        rmax[r] = fmaxf(rmax[r], __shfl_xor(rmax[r], off, 64));
#pragma unroll
                for (int r = 0; r < 4; ++r) {
                    const float mn = fmaxf(m_i[mi][r], rmax[r]);
                    alpha[r] = __expf(m_i[mi][r] - mn);
                    m_i[mi][r] = mn;
                    rsum[r] = 0.f;
                }
#pragma unroll
                for (int ni = 0; ni < 4; ++ni)
#pragma unroll
                    for (int r = 0; r < 4; ++r) {
                        const float pe = __expf(sacc[mi][ni][r] - m_i[mi][r]);
                        sacc[mi][ni][r] = pe;
                        rsum[r] += pe;
                    }
#pragma unroll
                for (int off = 1; off < 16; off <<= 1)
#pragma unroll
                    for (int r = 0; r < 4; ++r)
                        rsum[r] += __shfl_xor(rsum[r], off, 64);
#pragma unroll
                for (int r = 0; r < 4; ++r) {
                    l_i[mi][r] = l_i[mi][r] * alpha[r] + rsum[r];
#pragma unroll
                    for (int ni = 0; ni < 4; ++ni)
                        Ov[mi][ni][r] *= alpha[r];
                }
            }
            // P: C-layout -> A-layout via wave-private LDS rows
#pragma unroll
            for (int mi = 0; mi < 2; ++mi)
#pragma unroll
                for (int ni = 0; ni < 4; ++ni)
#pragma unroll
                    for (int r = 0; r < 4; ++r)
                        Ps[(wv * 32 + mi * 16 + quad * 4 + r) * AS_ + ni * 16 + l16] =
                            (__bf16)sacc[mi][ni][r];
            // O += P V
#pragma unroll
            for (int kk = 0; kk < 2; ++kk) {
                bf16x8 ap[2];
#pragma unroll
                for (int mi = 0; mi < 2; ++mi)
                    ap[mi] = *(const bf16x8*)(Ps + (wv * 32 + mi * 16 + l16) * AS_ + kk * 32 + quad * 8);
#pragma unroll
                for (int ni = 0; ni < 4; ++ni) {
                    const bf16x8 bv2 = *(const bf16x8*)(Vts + (ni * 16 + l16) * AS_ + kk * 32 + quad * 8);
#pragma unroll
                    for (int mi = 0; mi < 2; ++mi)
                        Ov[mi][ni] = __builtin_amdgcn_mfma_f32_16x16x32_bf16(
                            ap[mi], bv2, Ov[mi][ni], 0, 0, 0);
                }
            }
        }
        // epilogue
#pragma unroll
        for (int mi = 0; mi < 2; ++mi)
#pragma unroll
            for (int ni = 0; ni < 4; ++ni)
#pragma unroll
                for (int r = 0; r < 4; ++r) {
                    const int t = q0 + wv * 32 + mi * 16 + quad * 4 + r;
                    aout[((size_t)(bb * T_ + t)) * H_ + hh * HD_ + ni * 16 + l16] =
                        (__bf16)(Ov[mi][ni][r] / l_i[mi][r]);
                }
    }
}

// ---------------------------------------------------------------- launch
extern "C" void kernel_launch(void* const* d_in, const int* in_sizes, int n_in,
                              void* d_out, int out_size, void* d_ws, size_t ws_size,
                              hipStream_t stream)
{
    (void)in_sizes; (void)n_in; (void)out_size; (void)ws_size;
    const float* x       = (const float*)d_in[0];
    const float* w_attn  = (const float*)d_in[1];
    const float* b_attn  = (const float*)d_in[2];
    const float* w_aproj = (const float*)d_in[3];
    const float* b_aproj = (const float*)d_in[4];
    const float* ln1_w   = (const float*)d_in[5];
    const float* ln1_b   = (const float*)d_in[6];
    const float* ln2_w   = (const float*)d_in[7];
    const float* ln2_b   = (const float*)d_in[8];
    const float* w_fc    = (const float*)d_in[9];
    const float* b_fc    = (const float*)d_in[10];
    const float* w_mproj = (const float*)d_in[11];
    const float* b_mproj = (const float*)d_in[12];
    float* out = (float*)d_out;
    float* present = out + (size_t)M_ * H_;

    char* wp = (char*)d_ws;
    auto alloc = [&](size_t bytes) {
        void* p = (void*)wp; wp += (bytes + 255) & ~(size_t)255; return p;
    };
    __bf16* A1       = (__bf16*)alloc((size_t)M_ * H_ * 2);
    __bf16* A2       = (__bf16*)alloc((size_t)M_ * H_ * 2);
    __bf16* WattnT   = (__bf16*)alloc((size_t)3 * H_ * H_ * 2);
    __bf16* WaprojT  = (__bf16*)alloc((size_t)H_ * H_ * 2);
    __bf16* WfcT     = (__bf16*)alloc((size_t)4 * H_ * H_ * 2);
    __bf16* WmprojT  = (__bf16*)alloc((size_t)4 * H_ * H_ * 2);
    __bf16* qb       = (__bf16*)alloc((size_t)M_ * H_ * 2);
    __bf16* kb       = (__bf16*)alloc((size_t)M_ * H_ * 2);
    __bf16* vtb      = (__bf16*)alloc((size_t)M_ * H_ * 2);
    __bf16* attn_out = (__bf16*)alloc((size_t)M_ * H_ * 2);
    float*  x2       = (float*) alloc((size_t)M_ * H_ * 4);
    __bf16* Hbuf     = (__bf16*)alloc((size_t)M_ * 4 * H_ * 2);

    transpose_bf16<<<dim3(H_/32, 3*H_/32), 256, 0, stream>>>(w_attn,  WattnT,  H_,   3*H_);
    transpose_bf16<<<dim3(H_/32, H_/32),   256, 0, stream>>>(w_aproj, WaprojT, H_,   H_);
    transpose_bf16<<<dim3(H_/32, 4*H_/32), 256, 0, stream>>>(w_fc,    WfcT,    H_,   4*H_);
    transpose_bf16<<<dim3(4*H_/32, H_/32), 256, 0, stream>>>(w_mproj, WmprojT, 4*H_, H_);

    groupnorm_bf16<<<64, 256, 0, stream>>>(x, ln1_w, ln1_b, A1);
    gemm_qkv<<<dim3(M_/128, 3*H_/128), 256, 0, stream>>>(A1, WattnT, b_attn,
                                                         qb, kb, vtb, present);
    attn_kernel<<<dim3(8, B_*NH_), 256, 0, stream>>>(qb, kb, vtb, attn_out);
    gemm_resid<<<dim3(M_/128, H_/128), 256, 0, stream>>>(attn_out, WaprojT, b_aproj,
                                                         x, x2, H_, H_);
    groupnorm_bf16<<<64, 256, 0, stream>>>(x2, ln2_w, ln2_b, A2);
    gemm_gelu<<<dim3(M_/128, 4*H_/128), 256, 0, stream>>>(A2, WfcT, b_fc, Hbuf);
    gemm_resid<<<dim3(M_/128, H_/128), 256, 0, stream>>>(Hbuf, WmprojT, b_mproj,
                                                         x2, out, 4*H_, H_);
}

// Round 4
// 478.315 us; speedup vs baseline: 1.6032x; 1.4171x over previous
//
#include <hip/hip_runtime.h>

#define B_  2
#define T_  2048
#define H_  1024
#define NH_ 16
#define HD_ 64
#define M_  (B_*T_)   // 4096 rows
#define AS_ 72        // attention LDS row stride (64 data + 8 pad)

typedef __bf16 bf16x8 __attribute__((ext_vector_type(8)));
typedef float  floatx4 __attribute__((ext_vector_type(4)));

typedef __attribute__((address_space(1))) const unsigned int gas_u32;
typedef __attribute__((address_space(3))) unsigned int       las_u32;

__device__ __forceinline__ void gload_lds16(const __bf16* g, __bf16* l) {
    __builtin_amdgcn_global_load_lds((gas_u32*)g, (las_u32*)l, 16, 0, 0);
}

// ---------------------------------------------------------------- transpose
__global__ __launch_bounds__(256) void transpose_bf16(
    const float* __restrict__ in, __bf16* __restrict__ out, int K, int N)
{
    __shared__ float tile[32][33];
    const int k0 = blockIdx.x * 32, n0 = blockIdx.y * 32;
    const int tx = threadIdx.x & 31, ty = threadIdx.x >> 5;
#pragma unroll
    for (int i = 0; i < 32; i += 8)
        tile[ty + i][tx] = in[(size_t)(k0 + ty + i) * N + (n0 + tx)];
    __syncthreads();
#pragma unroll
    for (int i = 0; i < 32; i += 8)
        out[(size_t)(n0 + ty + i) * K + (k0 + tx)] = (__bf16)tile[tx][ty + i];
}

// ---------------------------------------------------------------- group norm (3-stage)
// stage 1: partial (sum, sumsq) per (bg, chunk); grid (64, 16)
__global__ __launch_bounds__(256) void gn_partial(
    const float* __restrict__ x, float2* __restrict__ part)
{
    const int bg = blockIdx.x, chunk = blockIdx.y;
    const int batch = bg >> 5, g = bg & 31;
    const float* xp = x + (size_t)batch * T_ * H_ + g * 32;
    float s = 0.f, ss = 0.f;
    for (int i = threadIdx.x; i < 128 * 32; i += 256) {
        const int t = chunk * 128 + (i >> 5), c = i & 31;
        const float v = xp[(size_t)t * H_ + c];
        s += v; ss += v * v;
    }
#pragma unroll
    for (int off = 32; off > 0; off >>= 1) {
        s  += __shfl_down(s,  off, 64);
        ss += __shfl_down(ss, off, 64);
    }
    __shared__ float rs[4], rss[4];
    const int wv = threadIdx.x >> 6, lane = threadIdx.x & 63;
    if (lane == 0) { rs[wv] = s; rss[wv] = ss; }
    __syncthreads();
    if (threadIdx.x == 0)
        part[bg * 16 + chunk] =
            make_float2(rs[0] + rs[1] + rs[2] + rs[3],
                        rss[0] + rss[1] + rss[2] + rss[3]);
}

// stage 2: mean/rstd per bg; 1 block x 64 threads
__global__ __launch_bounds__(64) void gn_finalize(
    const float2* __restrict__ part, float2* __restrict__ stats)
{
    const int bg = threadIdx.x;
    float s = 0.f, ss = 0.f;
#pragma unroll
    for (int i = 0; i < 16; ++i) {
        const float2 p = part[bg * 16 + i];
        s += p.x; ss += p.y;
    }
    const float inv = 1.f / (float)(T_ * 32);
    const float mean = s * inv;
    const float var  = ss * inv - mean * mean;
    stats[bg] = make_float2(mean, rsqrtf(var + 1e-5f));
}

// stage 3: normalize; grid M_*H_/1024, float4 per thread
__global__ __launch_bounds__(256) void gn_apply(
    const float* __restrict__ x, const float2* __restrict__ stats,
    const float* __restrict__ w, const float* __restrict__ bsc,
    __bf16* __restrict__ out)
{
    const size_t idx = ((size_t)blockIdx.x * 256 + threadIdx.x) * 4;
    const int h = (int)(idx & (H_ - 1));
    const int batch = (int)(idx >> 21);          // T_*H_ = 2^21
    const float2 mr = stats[batch * 32 + (h >> 5)];
    const float4 xv = *(const float4*)(x + idx);
    const float4 wv = *(const float4*)(w + h);
    const float4 bv = *(const float4*)(bsc + h);
    __bf16 o[4];
    o[0] = (__bf16)((xv.x - mr.x) * mr.y * wv.x + bv.x);
    o[1] = (__bf16)((xv.y - mr.x) * mr.y * wv.y + bv.y);
    o[2] = (__bf16)((xv.z - mr.x) * mr.y * wv.z + bv.z);
    o[3] = (__bf16)((xv.w - mr.x) * mr.y * wv.w + bv.w);
    *(uint2*)(out + idx) = *(uint2*)o;
}

// ---------------------------------------------------------------- GEMM core
// m97 recipe: global_load_lds width 16, LDS unpadded stride 32 (lds = base+tid*16B)
__device__ __forceinline__ void gemm_core(
    const __bf16* __restrict__ A, const __bf16* __restrict__ BT,
    int K, int m0, int n0, __bf16* As, __bf16* Bs, floatx4 (&acc)[4][4])
{
    const int tid  = threadIdx.x;
    const int lane = tid & 63, wv = tid >> 6;
    const int quad = lane >> 4, l16 = lane & 15;
    const int wm = (wv >> 1) * 64, wn = (wv & 1) * 64;
    const int r0 = tid >> 2, cc0 = (tid & 3) * 8;

    const __bf16* Ag0 = A  + (size_t)(m0 + r0)      * K + cc0;
    const __bf16* Ag1 = A  + (size_t)(m0 + r0 + 64) * K + cc0;
    const __bf16* Bg0 = BT + (size_t)(n0 + r0)      * K + cc0;
    const __bf16* Bg1 = BT + (size_t)(n0 + r0 + 64) * K + cc0;
    __bf16* asd0 = As + tid * 8;           // (r0*32+cc0) == tid*8
    __bf16* asd1 = As + 2048 + tid * 8;
    __bf16* bsd0 = Bs + tid * 8;
    __bf16* bsd1 = Bs + 2048 + tid * 8;

    for (int kt = 0; kt < K; kt += 32) {
        __syncthreads();                 // prev iter's LDS reads done
        gload_lds16(Ag0 + kt, asd0);
        gload_lds16(Ag1 + kt, asd1);
        gload_lds16(Bg0 + kt, bsd0);
        gload_lds16(Bg1 + kt, bsd1);
        __syncthreads();                 // drains vmcnt -> LDS filled
        bf16x8 af[4], bfg[4];
#pragma unroll
        for (int i = 0; i < 4; ++i)
            af[i]  = *(const bf16x8*)(As + (wm + i * 16 + l16) * 32 + quad * 8);
#pragma unroll
        for (int i = 0; i < 4; ++i)
            bfg[i] = *(const bf16x8*)(Bs + (wn + i * 16 + l16) * 32 + quad * 8);
#pragma unroll
        for (int mi = 0; mi < 4; ++mi)
#pragma unroll
            for (int ni = 0; ni < 4; ++ni)
                acc[mi][ni] = __builtin_amdgcn_mfma_f32_16x16x32_bf16(
                    af[mi], bfg[ni], acc[mi][ni], 0, 0, 0);
    }
}

#define GEMM_PROLOGUE(KVAL)                                             \
    __shared__ __align__(16) __bf16 As[128 * 32], Bs[128 * 32];         \
    const int m0 = blockIdx.x * 128, n0 = blockIdx.y * 128;             \
    floatx4 acc[4][4];                                                  \
    { floatx4 z = {0.f, 0.f, 0.f, 0.f};                                 \
      for (int i = 0; i < 4; ++i) for (int j = 0; j < 4; ++j) acc[i][j] = z; } \
    gemm_core(A, BT, (KVAL), m0, n0, As, Bs, acc);                      \
    const int tid = threadIdx.x, lane = tid & 63, wv = tid >> 6;        \
    const int quad = lane >> 4, l16 = lane & 15;                        \
    const int wm = (wv >> 1) * 64, wn = (wv & 1) * 64;                  \
    (void)tid;

// QKV: q,k bf16 [B,NH,T,HD]; v transposed bf16 [B,NH,HD,T]; present fp32
__global__ __launch_bounds__(256) void gemm_qkv(
    const __bf16* __restrict__ A, const __bf16* __restrict__ BT,
    const float* __restrict__ bias, __bf16* __restrict__ qb,
    __bf16* __restrict__ kb, __bf16* __restrict__ vtb,
    float* __restrict__ present)
{
    GEMM_PROLOGUE(H_)
#pragma unroll
    for (int ni = 0; ni < 4; ++ni) {
        const int col = n0 + wn + ni * 16 + l16;
        const float bv = bias[col];
        const int which = col >> 10, c = col & 1023, hh = c >> 6, d = c & 63;
#pragma unroll
        for (int mi = 0; mi < 4; ++mi)
#pragma unroll
            for (int r = 0; r < 4; ++r) {
                const int row = m0 + wm + mi * 16 + quad * 4 + r;
                const int bb = row >> 11, t = row & 2047;
                const float v = acc[mi][ni][r] + bv;
                const size_t idx = (((size_t)bb * NH_ + hh) * T_ + t) * HD_ + d;
                if (which == 0)      qb[idx] = (__bf16)v;
                else if (which == 1) { kb[idx] = (__bf16)v; present[idx] = v; }
                else { vtb[(((size_t)bb * NH_ + hh) * HD_ + d) * T_ + t] = (__bf16)v;
                       present[(size_t)B_ * NH_ * T_ * HD_ + idx] = v; }
            }
    }
}

__global__ __launch_bounds__(256) void gemm_resid(
    const __bf16* __restrict__ A, const __bf16* __restrict__ BT,
    const float* __restrict__ bias, const float* __restrict__ resid,
    float* __restrict__ out, int K, int N)
{
    GEMM_PROLOGUE(K)
#pragma unroll
    for (int ni = 0; ni < 4; ++ni) {
        const int col = n0 + wn + ni * 16 + l16;
        const float bv = bias[col];
#pragma unroll
        for (int mi = 0; mi < 4; ++mi)
#pragma unroll
            for (int r = 0; r < 4; ++r) {
                const int row = m0 + wm + mi * 16 + quad * 4 + r;
                const size_t idx = (size_t)row * N + col;
                out[idx] = acc[mi][ni][r] + bv + resid[idx];
            }
    }
}

__global__ __launch_bounds__(256) void gemm_gelu(
    const __bf16* __restrict__ A, const __bf16* __restrict__ BT,
    const float* __restrict__ bias, __bf16* __restrict__ out)
{
    GEMM_PROLOGUE(H_)
#pragma unroll
    for (int ni = 0; ni < 4; ++ni) {
        const int col = n0 + wn + ni * 16 + l16;
        const float bv = bias[col];
#pragma unroll
        for (int mi = 0; mi < 4; ++mi)
#pragma unroll
            for (int r = 0; r < 4; ++r) {
                const int row = m0 + wm + mi * 16 + quad * 4 + r;
                const float v = acc[mi][ni][r] + bv;
                const float g = 0.5f * v *
                    (1.f + tanhf(0.7978845608028654f * (v + 0.044715f * v * v * v)));
                out[(size_t)row * (4 * H_) + col] = (__bf16)g;
            }
    }
}

// ---------------------------------------------------------------- attention
// Balanced pairs: block handles q-supertiles p and 15-p (128 rows each) ->
// exactly 34 k-iterations/block. 4 waves x 32 q-rows. V pre-transposed.
__global__ __launch_bounds__(256) void attn_kernel(
    const __bf16* __restrict__ qb, const __bf16* __restrict__ kb,
    const __bf16* __restrict__ vtb, __bf16* __restrict__ aout)
{
    const int p = blockIdx.x, bh = blockIdx.y;
    const int bb = bh >> 4, hh = bh & 15;
    const __bf16* Q  = qb  + (size_t)bh * T_ * HD_;
    const __bf16* Kp = kb  + (size_t)bh * T_ * HD_;
    const __bf16* VT = vtb + (size_t)bh * HD_ * T_;
    __shared__ __align__(16) __bf16 Qs[128 * AS_], Ks[64 * AS_],
                                    Vts[64 * AS_], Ps[128 * AS_];

    const int tid = threadIdx.x, lane = tid & 63, wv = tid >> 6;
    const int quad = lane >> 4, l16 = lane & 15;
    const int r0 = tid >> 3, cc0 = (tid & 7) * 8;   // staging: 64x64 tiles

    for (int half = 0; half < 2; ++half) {
        const int sp = half ? (15 - p) : p;
        const int q0 = sp * 128;
        const int nkt = 2 * sp + 2;

        __syncthreads();   // prior half's Qs/Ps reads done
#pragma unroll
        for (int c = tid; c < 1024; c += 256) {
            const int r = c >> 3, cc = (c & 7) * 8;
            *(uint4*)(Qs + r * AS_ + cc) =
                *(const uint4*)(Q + (size_t)(q0 + r) * HD_ + cc);
        }

        float m_i[2][4], l_i[2][4];
        floatx4 Ov[2][4];
        {
            floatx4 z = {0.f, 0.f, 0.f, 0.f};
#pragma unroll
            for (int mi = 0; mi < 2; ++mi)
#pragma unroll
                for (int i = 0; i < 4; ++i)
                    { Ov[mi][i] = z; m_i[mi][i] = -1e30f; l_i[mi][i] = 0.f; }
        }

        // prefetch kt=0
        uint4 kr0, kr1, vr0, vr1;
        kr0 = *(const uint4*)(Kp + (size_t)(r0)      * HD_ + cc0);
        kr1 = *(const uint4*)(Kp + (size_t)(r0 + 32) * HD_ + cc0);
        vr0 = *(const uint4*)(VT + (size_t)(r0)      * T_ + cc0);
        vr1 = *(const uint4*)(VT + (size_t)(r0 + 32) * T_ + cc0);

        for (int kt = 0; kt < nkt; ++kt) {
            __syncthreads();   // prev iter's K/V reads done (+ Qs writes for kt=0)
            *(uint4*)(Ks  + r0 * AS_ + cc0)        = kr0;
            *(uint4*)(Ks  + (r0 + 32) * AS_ + cc0) = kr1;
            *(uint4*)(Vts + r0 * AS_ + cc0)        = vr0;
            *(uint4*)(Vts + (r0 + 32) * AS_ + cc0) = vr1;
            __syncthreads();
            if (kt + 1 < nkt) {   // prefetch next tile (overlaps compute)
                const int kn = kt + 1;
                kr0 = *(const uint4*)(Kp + (size_t)(kn * 64 + r0)      * HD_ + cc0);
                kr1 = *(const uint4*)(Kp + (size_t)(kn * 64 + r0 + 32) * HD_ + cc0);
                vr0 = *(const uint4*)(VT + (size_t)(r0)      * T_ + kn * 64 + cc0);
                vr1 = *(const uint4*)(VT + (size_t)(r0 + 32) * T_ + kn * 64 + cc0);
            }

            // S = Q K^T (2 m-tiles x 4 n-tiles per wave)
            floatx4 sacc[2][4];
            { floatx4 z = {0.f, 0.f, 0.f, 0.f};
#pragma unroll
              for (int mi = 0; mi < 2; ++mi)
#pragma unroll
                  for (int i = 0; i < 4; ++i) sacc[mi][i] = z; }
#pragma unroll
            for (int kk = 0; kk < 2; ++kk) {
                bf16x8 aq[2];
#pragma unroll
                for (int mi = 0; mi < 2; ++mi)
                    aq[mi] = *(const bf16x8*)(Qs + (wv * 32 + mi * 16 + l16) * AS_ + kk * 32 + quad * 8);
#pragma unroll
                for (int ni = 0; ni < 4; ++ni) {
                    const bf16x8 bk = *(const bf16x8*)(Ks + (ni * 16 + l16) * AS_ + kk * 32 + quad * 8);
#pragma unroll
                    for (int mi = 0; mi < 2; ++mi)
                        sacc[mi][ni] = __builtin_amdgcn_mfma_f32_16x16x32_bf16(
                            aq[mi], bk, sacc[mi][ni], 0, 0, 0);
                }
            }
            if (kt >= 2 * sp) {    // diagonal supertile: causal mask
#pragma unroll
                for (int mi = 0; mi < 2; ++mi)
#pragma unroll
                    for (int ni = 0; ni < 4; ++ni) {
                        const int key = kt * 64 + ni * 16 + l16;
#pragma unroll
                        for (int r = 0; r < 4; ++r)
                            if (key > q0 + wv * 32 + mi * 16 + quad * 4 + r)
                                sacc[mi][ni][r] = -1e30f;
                    }
            }
            // online softmax (8 rows/lane)
#pragma unroll
            for (int mi = 0; mi < 2; ++mi) {
                float rmax[4], alpha[4], rsum[4];
#pragma unroll
                for (int r = 0; r < 4; ++r)
                    rmax[r] = fmaxf(fmaxf(sacc[mi][0][r], sacc[mi][1][r]),
                                    fmaxf(sacc[mi][2][r], sacc[mi][3][r]));
#pragma unroll
                for (int off = 1; off < 16; off <<= 1)
#pragma unroll
                    for (int r = 0; r < 4; ++r)
                        rmax[r] = fmaxf(rmax[r], __shfl_xor(rmax[r], off, 64));
#pragma unroll
                for (int r = 0; r < 4; ++r) {
                    const float mn = fmaxf(m_i[mi][r], rmax[r]);
                    alpha[r] = __expf(m_i[mi][r] - mn);
                    m_i[mi][r] = mn;
                    rsum[r] = 0.f;
                }
#pragma unroll
                for (int ni = 0; ni < 4; ++ni)
#pragma unroll
                    for (int r = 0; r < 4; ++r) {
                        const float pe = __expf(sacc[mi][ni][r] - m_i[mi][r]);
                        sacc[mi][ni][r] = pe;
                        rsum[r] += pe;
                    }
#pragma unroll
                for (int off = 1; off < 16; off <<= 1)
#pragma unroll
                    for (int r = 0; r < 4; ++r)
                        rsum[r] += __shfl_xor(rsum[r], off, 64);
#pragma unroll
                for (int r = 0; r < 4; ++r) {
                    l_i[mi][r] = l_i[mi][r] * alpha[r] + rsum[r];
#pragma unroll
                    for (int ni = 0; ni < 4; ++ni)
                        Ov[mi][ni][r] *= alpha[r];
                }
            }
            // P: C-layout -> A-layout via wave-private LDS rows
#pragma unroll
            for (int mi = 0; mi < 2; ++mi)
#pragma unroll
                for (int ni = 0; ni < 4; ++ni)
#pragma unroll
                    for (int r = 0; r < 4; ++r)
                        Ps[(wv * 32 + mi * 16 + quad * 4 + r) * AS_ + ni * 16 + l16] =
                            (__bf16)sacc[mi][ni][r];
            // O += P V
#pragma unroll
            for (int kk = 0; kk < 2; ++kk) {
                bf16x8 ap[2];
#pragma unroll
                for (int mi = 0; mi < 2; ++mi)
                    ap[mi] = *(const bf16x8*)(Ps + (wv * 32 + mi * 16 + l16) * AS_ + kk * 32 + quad * 8);
#pragma unroll
                for (int ni = 0; ni < 4; ++ni) {
                    const bf16x8 bv2 = *(const bf16x8*)(Vts + (ni * 16 + l16) * AS_ + kk * 32 + quad * 8);
#pragma unroll
                    for (int mi = 0; mi < 2; ++mi)
                        Ov[mi][ni] = __builtin_amdgcn_mfma_f32_16x16x32_bf16(
                            ap[mi], bv2, Ov[mi][ni], 0, 0, 0);
                }
            }
        }
        // epilogue
#pragma unroll
        for (int mi = 0; mi < 2; ++mi)
#pragma unroll
            for (int ni = 0; ni < 4; ++ni)
#pragma unroll
                for (int r = 0; r < 4; ++r) {
                    const int t = q0 + wv * 32 + mi * 16 + quad * 4 + r;
                    aout[((size_t)(bb * T_ + t)) * H_ + hh * HD_ + ni * 16 + l16] =
                        (__bf16)(Ov[mi][ni][r] / l_i[mi][r]);
                }
    }
}

// ---------------------------------------------------------------- launch
extern "C" void kernel_launch(void* const* d_in, const int* in_sizes, int n_in,
                              void* d_out, int out_size, void* d_ws, size_t ws_size,
                              hipStream_t stream)
{
    (void)in_sizes; (void)n_in; (void)out_size; (void)ws_size;
    const float* x       = (const float*)d_in[0];
    const float* w_attn  = (const float*)d_in[1];
    const float* b_attn  = (const float*)d_in[2];
    const float* w_aproj = (const float*)d_in[3];
    const float* b_aproj = (const float*)d_in[4];
    const float* ln1_w   = (const float*)d_in[5];
    const float* ln1_b   = (const float*)d_in[6];
    const float* ln2_w   = (const float*)d_in[7];
    const float* ln2_b   = (const float*)d_in[8];
    const float* w_fc    = (const float*)d_in[9];
    const float* b_fc    = (const float*)d_in[10];
    const float* w_mproj = (const float*)d_in[11];
    const float* b_mproj = (const float*)d_in[12];
    float* out = (float*)d_out;
    float* present = out + (size_t)M_ * H_;

    char* wp = (char*)d_ws;
    auto alloc = [&](size_t bytes) {
        void* p = (void*)wp; wp += (bytes + 255) & ~(size_t)255; return p;
    };
    __bf16* A1       = (__bf16*)alloc((size_t)M_ * H_ * 2);
    __bf16* A2       = (__bf16*)alloc((size_t)M_ * H_ * 2);
    __bf16* WattnT   = (__bf16*)alloc((size_t)3 * H_ * H_ * 2);
    __bf16* WaprojT  = (__bf16*)alloc((size_t)H_ * H_ * 2);
    __bf16* WfcT     = (__bf16*)alloc((size_t)4 * H_ * H_ * 2);
    __bf16* WmprojT  = (__bf16*)alloc((size_t)4 * H_ * H_ * 2);
    __bf16* qb       = (__bf16*)alloc((size_t)M_ * H_ * 2);
    __bf16* kb       = (__bf16*)alloc((size_t)M_ * H_ * 2);
    __bf16* vtb      = (__bf16*)alloc((size_t)M_ * H_ * 2);
    __bf16* attn_out = (__bf16*)alloc((size_t)M_ * H_ * 2);
    float*  x2       = (float*) alloc((size_t)M_ * H_ * 4);
    __bf16* Hbuf     = (__bf16*)alloc((size_t)M_ * 4 * H_ * 2);
    float2* gn_part  = (float2*)alloc(64 * 16 * sizeof(float2));
    float2* gn_stats = (float2*)alloc(64 * sizeof(float2));

    transpose_bf16<<<dim3(H_/32, 3*H_/32), 256, 0, stream>>>(w_attn,  WattnT,  H_,   3*H_);
    transpose_bf16<<<dim3(H_/32, H_/32),   256, 0, stream>>>(w_aproj, WaprojT, H_,   H_);
    transpose_bf16<<<dim3(H_/32, 4*H_/32), 256, 0, stream>>>(w_fc,    WfcT,    H_,   4*H_);
    transpose_bf16<<<dim3(4*H_/32, H_/32), 256, 0, stream>>>(w_mproj, WmprojT, 4*H_, H_);

    gn_partial <<<dim3(64, 16), 256, 0, stream>>>(x, gn_part);
    gn_finalize<<<1, 64, 0, stream>>>(gn_part, gn_stats);
    gn_apply   <<<M_*H_/1024, 256, 0, stream>>>(x, gn_stats, ln1_w, ln1_b, A1);

    gemm_qkv<<<dim3(M_/128, 3*H_/128), 256, 0, stream>>>(A1, WattnT, b_attn,
                                                         qb, kb, vtb, present);
    attn_kernel<<<dim3(8, B_*NH_), 256, 0, stream>>>(qb, kb, vtb, attn_out);
    gemm_resid<<<dim3(M_/128, H_/128), 256, 0, stream>>>(attn_out, WaprojT, b_aproj,
                                                         x, x2, H_, H_);

    gn_partial <<<dim3(64, 16), 256, 0, stream>>>(x2, gn_part);
    gn_finalize<<<1, 64, 0, stream>>>(gn_part, gn_stats);
    gn_apply   <<<M_*H_/1024, 256, 0, stream>>>(x2, gn_stats, ln2_w, ln2_b, A2);

    gemm_gelu<<<dim3(M_/128, 4*H_/128), 256, 0, stream>>>(A2, WfcT, b_fc, Hbuf);
    gemm_resid<<<dim3(M_/128, H_/128), 256, 0, stream>>>(Hbuf, WmprojT, b_mproj,
                                                         x2, out, 4*H_, H_);
}

// Round 5
// 462.872 us; speedup vs baseline: 1.6567x; 1.0334x over previous
//
#include <hip/hip_runtime.h>

#define B_  2
#define T_  2048
#define H_  1024
#define NH_ 16
#define HD_ 64
#define M_  (B_*T_)   // 4096 rows
#define AS_ 72        // attention LDS row stride (64 data + 8 pad)

typedef __bf16 bf16x8 __attribute__((ext_vector_type(8)));
typedef float  floatx4 __attribute__((ext_vector_type(4)));

typedef __attribute__((address_space(1))) const unsigned int gas_u32;
typedef __attribute__((address_space(3))) unsigned int       las_u32;

__device__ __forceinline__ void gload_lds16(const __bf16* g, __bf16* l) {
    __builtin_amdgcn_global_load_lds((gas_u32*)g, (las_u32*)l, 16, 0, 0);
}

// ---------------------------------------------------------------- transpose
__global__ __launch_bounds__(256) void transpose_bf16(
    const float* __restrict__ in, __bf16* __restrict__ out, int K, int N)
{
    __shared__ float tile[32][33];
    const int k0 = blockIdx.x * 32, n0 = blockIdx.y * 32;
    const int tx = threadIdx.x & 31, ty = threadIdx.x >> 5;
#pragma unroll
    for (int i = 0; i < 32; i += 8)
        tile[ty + i][tx] = in[(size_t)(k0 + ty + i) * N + (n0 + tx)];
    __syncthreads();
#pragma unroll
    for (int i = 0; i < 32; i += 8)
        out[(size_t)(n0 + ty + i) * K + (k0 + tx)] = (__bf16)tile[tx][ty + i];
}

// ---------------------------------------------------------------- group norm (3-stage)
__global__ __launch_bounds__(256) void gn_partial(
    const float* __restrict__ x, float2* __restrict__ part)
{
    const int bg = blockIdx.x, chunk = blockIdx.y;
    const int batch = bg >> 5, g = bg & 31;
    const float* xp = x + (size_t)batch * T_ * H_ + g * 32;
    float s = 0.f, ss = 0.f;
    for (int i = threadIdx.x; i < 128 * 32; i += 256) {
        const int t = chunk * 128 + (i >> 5), c = i & 31;
        const float v = xp[(size_t)t * H_ + c];
        s += v; ss += v * v;
    }
#pragma unroll
    for (int off = 32; off > 0; off >>= 1) {
        s  += __shfl_down(s,  off, 64);
        ss += __shfl_down(ss, off, 64);
    }
    __shared__ float rs[4], rss[4];
    const int wv = threadIdx.x >> 6, lane = threadIdx.x & 63;
    if (lane == 0) { rs[wv] = s; rss[wv] = ss; }
    __syncthreads();
    if (threadIdx.x == 0)
        part[bg * 16 + chunk] =
            make_float2(rs[0] + rs[1] + rs[2] + rs[3],
                        rss[0] + rss[1] + rss[2] + rss[3]);
}

__global__ __launch_bounds__(64) void gn_finalize(
    const float2* __restrict__ part, float2* __restrict__ stats)
{
    const int bg = threadIdx.x;
    float s = 0.f, ss = 0.f;
#pragma unroll
    for (int i = 0; i < 16; ++i) {
        const float2 p = part[bg * 16 + i];
        s += p.x; ss += p.y;
    }
    const float inv = 1.f / (float)(T_ * 32);
    const float mean = s * inv;
    const float var  = ss * inv - mean * mean;
    stats[bg] = make_float2(mean, rsqrtf(var + 1e-5f));
}

__global__ __launch_bounds__(256) void gn_apply(
    const float* __restrict__ x, const float2* __restrict__ stats,
    const float* __restrict__ w, const float* __restrict__ bsc,
    __bf16* __restrict__ out)
{
    const size_t idx = ((size_t)blockIdx.x * 256 + threadIdx.x) * 4;
    const int h = (int)(idx & (H_ - 1));
    const int batch = (int)(idx >> 21);          // T_*H_ = 2^21
    const float2 mr = stats[batch * 32 + (h >> 5)];
    const float4 xv = *(const float4*)(x + idx);
    const float4 wv = *(const float4*)(w + h);
    const float4 bv = *(const float4*)(bsc + h);
    __bf16 o[4];
    o[0] = (__bf16)((xv.x - mr.x) * mr.y * wv.x + bv.x);
    o[1] = (__bf16)((xv.y - mr.x) * mr.y * wv.y + bv.y);
    o[2] = (__bf16)((xv.z - mr.x) * mr.y * wv.z + bv.z);
    o[3] = (__bf16)((xv.w - mr.x) * mr.y * wv.w + bv.w);
    *(uint2*)(out + idx) = *(uint2*)o;
}

// ---------------------------------------------------------------- GEMM core 128x128
__device__ __forceinline__ void gemm_core(
    const __bf16* __restrict__ A, const __bf16* __restrict__ BT,
    int K, int m0, int n0, __bf16* As, __bf16* Bs, floatx4 (&acc)[4][4])
{
    const int tid  = threadIdx.x;
    const int lane = tid & 63, wv = tid >> 6;
    const int quad = lane >> 4, l16 = lane & 15;
    const int wm = (wv >> 1) * 64, wn = (wv & 1) * 64;
    const int r0 = tid >> 2, cc0 = (tid & 3) * 8;

    const __bf16* Ag0 = A  + (size_t)(m0 + r0)      * K + cc0;
    const __bf16* Ag1 = A  + (size_t)(m0 + r0 + 64) * K + cc0;
    const __bf16* Bg0 = BT + (size_t)(n0 + r0)      * K + cc0;
    const __bf16* Bg1 = BT + (size_t)(n0 + r0 + 64) * K + cc0;
    __bf16* asd0 = As + tid * 8;
    __bf16* asd1 = As + 2048 + tid * 8;
    __bf16* bsd0 = Bs + tid * 8;
    __bf16* bsd1 = Bs + 2048 + tid * 8;

    for (int kt = 0; kt < K; kt += 32) {
        __syncthreads();
        gload_lds16(Ag0 + kt, asd0);
        gload_lds16(Ag1 + kt, asd1);
        gload_lds16(Bg0 + kt, bsd0);
        gload_lds16(Bg1 + kt, bsd1);
        __syncthreads();
        bf16x8 af[4], bfg[4];
#pragma unroll
        for (int i = 0; i < 4; ++i)
            af[i]  = *(const bf16x8*)(As + (wm + i * 16 + l16) * 32 + quad * 8);
#pragma unroll
        for (int i = 0; i < 4; ++i)
            bfg[i] = *(const bf16x8*)(Bs + (wn + i * 16 + l16) * 32 + quad * 8);
#pragma unroll
        for (int mi = 0; mi < 4; ++mi)
#pragma unroll
            for (int ni = 0; ni < 4; ++ni)
                acc[mi][ni] = __builtin_amdgcn_mfma_f32_16x16x32_bf16(
                    af[mi], bfg[ni], acc[mi][ni], 0, 0, 0);
    }
}

#define GEMM_PROLOGUE(KVAL)                                             \
    __shared__ __align__(16) __bf16 As[128 * 32], Bs[128 * 32];         \
    const int m0 = blockIdx.x * 128, n0 = blockIdx.y * 128;             \
    floatx4 acc[4][4];                                                  \
    { floatx4 z = {0.f, 0.f, 0.f, 0.f};                                 \
      for (int i = 0; i < 4; ++i) for (int j = 0; j < 4; ++j) acc[i][j] = z; } \
    gemm_core(A, BT, (KVAL), m0, n0, As, Bs, acc);                      \
    const int tid = threadIdx.x, lane = tid & 63, wv = tid >> 6;        \
    const int quad = lane >> 4, l16 = lane & 15;                        \
    const int wm = (wv >> 1) * 64, wn = (wv & 1) * 64;                  \
    (void)tid;

// QKV: q,k bf16 [B,NH,T,HD]; v transposed bf16 [B,NH,HD,T]; present fp32
__global__ __launch_bounds__(256) void gemm_qkv(
    const __bf16* __restrict__ A, const __bf16* __restrict__ BT,
    const float* __restrict__ bias, __bf16* __restrict__ qb,
    __bf16* __restrict__ kb, __bf16* __restrict__ vtb,
    float* __restrict__ present)
{
    GEMM_PROLOGUE(H_)
#pragma unroll
    for (int ni = 0; ni < 4; ++ni) {
        const int col = n0 + wn + ni * 16 + l16;
        const float bv = bias[col];
        const int which = col >> 10, c = col & 1023, hh = c >> 6, d = c & 63;
#pragma unroll
        for (int mi = 0; mi < 4; ++mi)
#pragma unroll
            for (int r = 0; r < 4; ++r) {
                const int row = m0 + wm + mi * 16 + quad * 4 + r;
                const int bb = row >> 11, t = row & 2047;
                const float v = acc[mi][ni][r] + bv;
                const size_t idx = (((size_t)bb * NH_ + hh) * T_ + t) * HD_ + d;
                if (which == 0)      qb[idx] = (__bf16)v;
                else if (which == 1) { kb[idx] = (__bf16)v; present[idx] = v; }
                else { vtb[(((size_t)bb * NH_ + hh) * HD_ + d) * T_ + t] = (__bf16)v;
                       present[(size_t)B_ * NH_ * T_ * HD_ + idx] = v; }
            }
    }
}

__global__ __launch_bounds__(256) void gemm_gelu(
    const __bf16* __restrict__ A, const __bf16* __restrict__ BT,
    const float* __restrict__ bias, __bf16* __restrict__ out)
{
    GEMM_PROLOGUE(H_)
#pragma unroll
    for (int ni = 0; ni < 4; ++ni) {
        const int col = n0 + wn + ni * 16 + l16;
        const float bv = bias[col];
#pragma unroll
        for (int mi = 0; mi < 4; ++mi)
#pragma unroll
            for (int r = 0; r < 4; ++r) {
                const int row = m0 + wm + mi * 16 + quad * 4 + r;
                const float v = acc[mi][ni][r] + bv;
                const float g = 0.5f * v *
                    (1.f + tanhf(0.7978845608028654f * (v + 0.044715f * v * v * v)));
                out[(size_t)row * (4 * H_) + col] = (__bf16)g;
            }
    }
}

// ---------------------------------------------------------------- GEMM 128x64 + resid
// For N=1024 outputs: grid (M/128, N/64) = 512 blocks -> 2 blocks/CU overlap.
// 4 waves in 2x2; wave tile 64x32 (acc[4][2]). Staging: A 8KB (2 ld), B 4KB (1 ld).
__global__ __launch_bounds__(256) void gemm_resid_n64(
    const __bf16* __restrict__ A, const __bf16* __restrict__ BT,
    const float* __restrict__ bias, const float* __restrict__ resid,
    float* __restrict__ out, int K, int N)
{
    __shared__ __align__(16) __bf16 As[128 * 32], Bs[64 * 32];
    const int m0 = blockIdx.x * 128, n0 = blockIdx.y * 64;
    const int tid  = threadIdx.x;
    const int lane = tid & 63, wv = tid >> 6;
    const int quad = lane >> 4, l16 = lane & 15;
    const int wm = (wv >> 1) * 64, wn = (wv & 1) * 32;
    const int r0 = tid >> 2, cc0 = (tid & 3) * 8;

    floatx4 acc[4][2];
    { floatx4 z = {0.f, 0.f, 0.f, 0.f};
#pragma unroll
      for (int i = 0; i < 4; ++i) { acc[i][0] = z; acc[i][1] = z; } }

    const __bf16* Ag0 = A  + (size_t)(m0 + r0)      * K + cc0;
    const __bf16* Ag1 = A  + (size_t)(m0 + r0 + 64) * K + cc0;
    const __bf16* Bg0 = BT + (size_t)(n0 + r0)      * K + cc0;   // 64 rows
    __bf16* asd0 = As + tid * 8;
    __bf16* asd1 = As + 2048 + tid * 8;
    __bf16* bsd0 = Bs + tid * 8;

    for (int kt = 0; kt < K; kt += 32) {
        __syncthreads();
        gload_lds16(Ag0 + kt, asd0);
        gload_lds16(Ag1 + kt, asd1);
        gload_lds16(Bg0 + kt, bsd0);
        __syncthreads();
        bf16x8 af[4], bfg[2];
#pragma unroll
        for (int i = 0; i < 4; ++i)
            af[i]  = *(const bf16x8*)(As + (wm + i * 16 + l16) * 32 + quad * 8);
#pragma unroll
        for (int i = 0; i < 2; ++i)
            bfg[i] = *(const bf16x8*)(Bs + (wn + i * 16 + l16) * 32 + quad * 8);
#pragma unroll
        for (int mi = 0; mi < 4; ++mi)
#pragma unroll
            for (int ni = 0; ni < 2; ++ni)
                acc[mi][ni] = __builtin_amdgcn_mfma_f32_16x16x32_bf16(
                    af[mi], bfg[ni], acc[mi][ni], 0, 0, 0);
    }

#pragma unroll
    for (int ni = 0; ni < 2; ++ni) {
        const int col = n0 + wn + ni * 16 + l16;
        const float bv = bias[col];
#pragma unroll
        for (int mi = 0; mi < 4; ++mi)
#pragma unroll
            for (int r = 0; r < 4; ++r) {
                const int row = m0 + wm + mi * 16 + quad * 4 + r;
                const size_t idx = (size_t)row * N + col;
                out[idx] = acc[mi][ni][r] + bv + resid[idx];
            }
    }
}

// ---------------------------------------------------------------- attention
__global__ __launch_bounds__(256) void attn_kernel(
    const __bf16* __restrict__ qb, const __bf16* __restrict__ kb,
    const __bf16* __restrict__ vtb, __bf16* __restrict__ aout)
{
    const int p = blockIdx.x, bh = blockIdx.y;
    const int bb = bh >> 4, hh = bh & 15;
    const __bf16* Q  = qb  + (size_t)bh * T_ * HD_;
    const __bf16* Kp = kb  + (size_t)bh * T_ * HD_;
    const __bf16* VT = vtb + (size_t)bh * HD_ * T_;
    __shared__ __align__(16) __bf16 Qs[128 * AS_], Ks[64 * AS_],
                                    Vts[64 * AS_], Ps[128 * AS_];

    const int tid = threadIdx.x, lane = tid & 63, wv = tid >> 6;
    const int quad = lane >> 4, l16 = lane & 15;
    const int r0 = tid >> 3, cc0 = (tid & 7) * 8;

    for (int half = 0; half < 2; ++half) {
        const int sp = half ? (15 - p) : p;
        const int q0 = sp * 128;
        const int nkt = 2 * sp + 2;

        __syncthreads();
#pragma unroll
        for (int c = tid; c < 1024; c += 256) {
            const int r = c >> 3, cc = (c & 7) * 8;
            *(uint4*)(Qs + r * AS_ + cc) =
                *(const uint4*)(Q + (size_t)(q0 + r) * HD_ + cc);
        }

        float m_i[2][4], l_i[2][4];
        floatx4 Ov[2][4];
        {
            floatx4 z = {0.f, 0.f, 0.f, 0.f};
#pragma unroll
            for (int mi = 0; mi < 2; ++mi)
#pragma unroll
                for (int i = 0; i < 4; ++i)
                    { Ov[mi][i] = z; m_i[mi][i] = -1e30f; l_i[mi][i] = 0.f; }
        }

        uint4 kr0, kr1, vr0, vr1;
        kr0 = *(const uint4*)(Kp + (size_t)(r0)      * HD_ + cc0);
        kr1 = *(const uint4*)(Kp + (size_t)(r0 + 32) * HD_ + cc0);
        vr0 = *(const uint4*)(VT + (size_t)(r0)      * T_ + cc0);
        vr1 = *(const uint4*)(VT + (size_t)(r0 + 32) * T_ + cc0);

        for (int kt = 0; kt < nkt; ++kt) {
            __syncthreads();
            *(uint4*)(Ks  + r0 * AS_ + cc0)        = kr0;
            *(uint4*)(Ks  + (r0 + 32) * AS_ + cc0) = kr1;
            *(uint4*)(Vts + r0 * AS_ + cc0)        = vr0;
            *(uint4*)(Vts + (r0 + 32) * AS_ + cc0) = vr1;
            __syncthreads();
            if (kt + 1 < nkt) {
                const int kn = kt + 1;
                kr0 = *(const uint4*)(Kp + (size_t)(kn * 64 + r0)      * HD_ + cc0);
                kr1 = *(const uint4*)(Kp + (size_t)(kn * 64 + r0 + 32) * HD_ + cc0);
                vr0 = *(const uint4*)(VT + (size_t)(r0)      * T_ + kn * 64 + cc0);
                vr1 = *(const uint4*)(VT + (size_t)(r0 + 32) * T_ + kn * 64 + cc0);
            }

            floatx4 sacc[2][4];
            { floatx4 z = {0.f, 0.f, 0.f, 0.f};
#pragma unroll
              for (int mi = 0; mi < 2; ++mi)
#pragma unroll
                  for (int i = 0; i < 4; ++i) sacc[mi][i] = z; }
#pragma unroll
            for (int kk = 0; kk < 2; ++kk) {
                bf16x8 aq[2];
#pragma unroll
                for (int mi = 0; mi < 2; ++mi)
                    aq[mi] = *(const bf16x8*)(Qs + (wv * 32 + mi * 16 + l16) * AS_ + kk * 32 + quad * 8);
#pragma unroll
                for (int ni = 0; ni < 4; ++ni) {
                    const bf16x8 bk = *(const bf16x8*)(Ks + (ni * 16 + l16) * AS_ + kk * 32 + quad * 8);
#pragma unroll
                    for (int mi = 0; mi < 2; ++mi)
                        sacc[mi][ni] = __builtin_amdgcn_mfma_f32_16x16x32_bf16(
                            aq[mi], bk, sacc[mi][ni], 0, 0, 0);
                }
            }
            if (kt >= 2 * sp) {
#pragma unroll
                for (int mi = 0; mi < 2; ++mi)
#pragma unroll
                    for (int ni = 0; ni < 4; ++ni) {
                        const int key = kt * 64 + ni * 16 + l16;
#pragma unroll
                        for (int r = 0; r < 4; ++r)
                            if (key > q0 + wv * 32 + mi * 16 + quad * 4 + r)
                                sacc[mi][ni][r] = -1e30f;
                    }
            }
#pragma unroll
            for (int mi = 0; mi < 2; ++mi) {
                float rmax[4], alpha[4], rsum[4];
#pragma unroll
                for (int r = 0; r < 4; ++r)
                    rmax[r] = fmaxf(fmaxf(sacc[mi][0][r], sacc[mi][1][r]),
                                    fmaxf(sacc[mi][2][r], sacc[mi][3][r]));
#pragma unroll
                for (int off = 1; off < 16; off <<= 1)
#pragma unroll
                    for (int r = 0; r < 4; ++r)
                        rmax[r] = fmaxf(rmax[r], __shfl_xor(rmax[r], off, 64));
#pragma unroll
                for (int r = 0; r < 4; ++r) {
                    const float mn = fmaxf(m_i[mi][r], rmax[r]);
                    alpha[r] = __expf(m_i[mi][r] - mn);
                    m_i[mi][r] = mn;
                    rsum[r] = 0.f;
                }
#pragma unroll
                for (int ni = 0; ni < 4; ++ni)
#pragma unroll
                    for (int r = 0; r < 4; ++r) {
                        const float pe = __expf(sacc[mi][ni][r] - m_i[mi][r]);
                        sacc[mi][ni][r] = pe;
                        rsum[r] += pe;
                    }
#pragma unroll
                for (int off = 1; off < 16; off <<= 1)
#pragma unroll
                    for (int r = 0; r < 4; ++r)
                        rsum[r] += __shfl_xor(rsum[r], off, 64);
#pragma unroll
                for (int r = 0; r < 4; ++r) {
                    l_i[mi][r] = l_i[mi][r] * alpha[r] + rsum[r];
#pragma unroll
                    for (int ni = 0; ni < 4; ++ni)
                        Ov[mi][ni][r] *= alpha[r];
                }
            }
#pragma unroll
            for (int mi = 0; mi < 2; ++mi)
#pragma unroll
                for (int ni = 0; ni < 4; ++ni)
#pragma unroll
                    for (int r = 0; r < 4; ++r)
                        Ps[(wv * 32 + mi * 16 + quad * 4 + r) * AS_ + ni * 16 + l16] =
                            (__bf16)sacc[mi][ni][r];
#pragma unroll
            for (int kk = 0; kk < 2; ++kk) {
                bf16x8 ap[2];
#pragma unroll
                for (int mi = 0; mi < 2; ++mi)
                    ap[mi] = *(const bf16x8*)(Ps + (wv * 32 + mi * 16 + l16) * AS_ + kk * 32 + quad * 8);
#pragma unroll
                for (int ni = 0; ni < 4; ++ni) {
                    const bf16x8 bv2 = *(const bf16x8*)(Vts + (ni * 16 + l16) * AS_ + kk * 32 + quad * 8);
#pragma unroll
                    for (int mi = 0; mi < 2; ++mi)
                        Ov[mi][ni] = __builtin_amdgcn_mfma_f32_16x16x32_bf16(
                            ap[mi], bv2, Ov[mi][ni], 0, 0, 0);
                }
            }
        }
#pragma unroll
        for (int mi = 0; mi < 2; ++mi)
#pragma unroll
            for (int ni = 0; ni < 4; ++ni)
#pragma unroll
                for (int r = 0; r < 4; ++r) {
                    const int t = q0 + wv * 32 + mi * 16 + quad * 4 + r;
                    aout[((size_t)(bb * T_ + t)) * H_ + hh * HD_ + ni * 16 + l16] =
                        (__bf16)(Ov[mi][ni][r] / l_i[mi][r]);
                }
    }
}

// ---------------------------------------------------------------- launch
extern "C" void kernel_launch(void* const* d_in, const int* in_sizes, int n_in,
                              void* d_out, int out_size, void* d_ws, size_t ws_size,
                              hipStream_t stream)
{
    (void)in_sizes; (void)n_in; (void)out_size; (void)ws_size;
    const float* x       = (const float*)d_in[0];
    const float* w_attn  = (const float*)d_in[1];
    const float* b_attn  = (const float*)d_in[2];
    const float* w_aproj = (const float*)d_in[3];
    const float* b_aproj = (const float*)d_in[4];
    const float* ln1_w   = (const float*)d_in[5];
    const float* ln1_b   = (const float*)d_in[6];
    const float* ln2_w   = (const float*)d_in[7];
    const float* ln2_b   = (const float*)d_in[8];
    const float* w_fc    = (const float*)d_in[9];
    const float* b_fc    = (const float*)d_in[10];
    const float* w_mproj = (const float*)d_in[11];
    const float* b_mproj = (const float*)d_in[12];
    float* out = (float*)d_out;
    float* present = out + (size_t)M_ * H_;

    char* wp = (char*)d_ws;
    auto alloc = [&](size_t bytes) {
        void* p = (void*)wp; wp += (bytes + 255) & ~(size_t)255; return p;
    };
    __bf16* A1       = (__bf16*)alloc((size_t)M_ * H_ * 2);
    __bf16* A2       = (__bf16*)alloc((size_t)M_ * H_ * 2);
    __bf16* WattnT   = (__bf16*)alloc((size_t)3 * H_ * H_ * 2);
    __bf16* WaprojT  = (__bf16*)alloc((size_t)H_ * H_ * 2);
    __bf16* WfcT     = (__bf16*)alloc((size_t)4 * H_ * H_ * 2);
    __bf16* WmprojT  = (__bf16*)alloc((size_t)4 * H_ * H_ * 2);
    __bf16* qb       = (__bf16*)alloc((size_t)M_ * H_ * 2);
    __bf16* kb       = (__bf16*)alloc((size_t)M_ * H_ * 2);
    __bf16* vtb      = (__bf16*)alloc((size_t)M_ * H_ * 2);
    __bf16* attn_out = (__bf16*)alloc((size_t)M_ * H_ * 2);
    float*  x2       = (float*) alloc((size_t)M_ * H_ * 4);
    __bf16* Hbuf     = (__bf16*)alloc((size_t)M_ * 4 * H_ * 2);
    float2* gn_part  = (float2*)alloc(64 * 16 * sizeof(float2));
    float2* gn_stats = (float2*)alloc(64 * sizeof(float2));

    transpose_bf16<<<dim3(H_/32, 3*H_/32), 256, 0, stream>>>(w_attn,  WattnT,  H_,   3*H_);
    transpose_bf16<<<dim3(H_/32, H_/32),   256, 0, stream>>>(w_aproj, WaprojT, H_,   H_);
    transpose_bf16<<<dim3(H_/32, 4*H_/32), 256, 0, stream>>>(w_fc,    WfcT,    H_,   4*H_);
    transpose_bf16<<<dim3(4*H_/32, H_/32), 256, 0, stream>>>(w_mproj, WmprojT, 4*H_, H_);

    gn_partial <<<dim3(64, 16), 256, 0, stream>>>(x, gn_part);
    gn_finalize<<<1, 64, 0, stream>>>(gn_part, gn_stats);
    gn_apply   <<<M_*H_/1024, 256, 0, stream>>>(x, gn_stats, ln1_w, ln1_b, A1);

    gemm_qkv<<<dim3(M_/128, 3*H_/128), 256, 0, stream>>>(A1, WattnT, b_attn,
                                                         qb, kb, vtb, present);
    attn_kernel<<<dim3(8, B_*NH_), 256, 0, stream>>>(qb, kb, vtb, attn_out);
    gemm_resid_n64<<<dim3(M_/128, H_/64), 256, 0, stream>>>(attn_out, WaprojT, b_aproj,
                                                            x, x2, H_, H_);

    gn_partial <<<dim3(64, 16), 256, 0, stream>>>(x2, gn_part);
    gn_finalize<<<1, 64, 0, stream>>>(gn_part, gn_stats);
    gn_apply   <<<M_*H_/1024, 256, 0, stream>>>(x2, gn_stats, ln2_w, ln2_b, A2);

    gemm_gelu<<<dim3(M_/128, 4*H_/128), 256, 0, stream>>>(A2, WfcT, b_fc, Hbuf);
    gemm_resid_n64<<<dim3(M_/128, H_/64), 256, 0, stream>>>(Hbuf, WmprojT, b_mproj,
                                                            x2, out, 4*H_, H_);
}

// Round 6
// 432.560 us; speedup vs baseline: 1.7728x; 1.0701x over previous
//
#include <hip/hip_runtime.h>

#define B_  2
#define T_  2048
#define H_  1024
#define NH_ 16
#define HD_ 64
#define M_  (B_*T_)   // 4096 rows
#define PS_ 72        // P-matrix LDS row stride (64 data + 8 pad)

typedef __bf16 bf16x8 __attribute__((ext_vector_type(8)));
typedef float  floatx4 __attribute__((ext_vector_type(4)));

typedef __attribute__((address_space(1))) const unsigned int gas_u32;
typedef __attribute__((address_space(3))) unsigned int       las_u32;

__device__ __forceinline__ void gload_lds16(const __bf16* g, __bf16* l) {
    __builtin_amdgcn_global_load_lds((gas_u32*)g, (las_u32*)l, 16, 0, 0);
}

// ---------------------------------------------------------------- transpose
__global__ __launch_bounds__(256) void transpose_bf16(
    const float* __restrict__ in, __bf16* __restrict__ out, int K, int N)
{
    __shared__ float tile[32][33];
    const int k0 = blockIdx.x * 32, n0 = blockIdx.y * 32;
    const int tx = threadIdx.x & 31, ty = threadIdx.x >> 5;
#pragma unroll
    for (int i = 0; i < 32; i += 8)
        tile[ty + i][tx] = in[(size_t)(k0 + ty + i) * N + (n0 + tx)];
    __syncthreads();
#pragma unroll
    for (int i = 0; i < 32; i += 8)
        out[(size_t)(n0 + ty + i) * K + (k0 + tx)] = (__bf16)tile[tx][ty + i];
}

// ---------------------------------------------------------------- group norm (3-stage)
__global__ __launch_bounds__(256) void gn_partial(
    const float* __restrict__ x, float2* __restrict__ part)
{
    const int bg = blockIdx.x, chunk = blockIdx.y;
    const int batch = bg >> 5, g = bg & 31;
    const float* xp = x + (size_t)batch * T_ * H_ + g * 32;
    float s = 0.f, ss = 0.f;
    for (int i = threadIdx.x; i < 128 * 32; i += 256) {
        const int t = chunk * 128 + (i >> 5), c = i & 31;
        const float v = xp[(size_t)t * H_ + c];
        s += v; ss += v * v;
    }
#pragma unroll
    for (int off = 32; off > 0; off >>= 1) {
        s  += __shfl_down(s,  off, 64);
        ss += __shfl_down(ss, off, 64);
    }
    __shared__ float rs[4], rss[4];
    const int wv = threadIdx.x >> 6, lane = threadIdx.x & 63;
    if (lane == 0) { rs[wv] = s; rss[wv] = ss; }
    __syncthreads();
    if (threadIdx.x == 0)
        part[bg * 16 + chunk] =
            make_float2(rs[0] + rs[1] + rs[2] + rs[3],
                        rss[0] + rss[1] + rss[2] + rss[3]);
}

__global__ __launch_bounds__(64) void gn_finalize(
    const float2* __restrict__ part, float2* __restrict__ stats)
{
    const int bg = threadIdx.x;
    float s = 0.f, ss = 0.f;
#pragma unroll
    for (int i = 0; i < 16; ++i) {
        const float2 p = part[bg * 16 + i];
        s += p.x; ss += p.y;
    }
    const float inv = 1.f / (float)(T_ * 32);
    const float mean = s * inv;
    const float var  = ss * inv - mean * mean;
    stats[bg] = make_float2(mean, rsqrtf(var + 1e-5f));
}

__global__ __launch_bounds__(256) void gn_apply(
    const float* __restrict__ x, const float2* __restrict__ stats,
    const float* __restrict__ w, const float* __restrict__ bsc,
    __bf16* __restrict__ out)
{
    const size_t idx = ((size_t)blockIdx.x * 256 + threadIdx.x) * 4;
    const int h = (int)(idx & (H_ - 1));
    const int batch = (int)(idx >> 21);          // T_*H_ = 2^21
    const float2 mr = stats[batch * 32 + (h >> 5)];
    const float4 xv = *(const float4*)(x + idx);
    const float4 wv = *(const float4*)(w + h);
    const float4 bv = *(const float4*)(bsc + h);
    __bf16 o[4];
    o[0] = (__bf16)((xv.x - mr.x) * mr.y * wv.x + bv.x);
    o[1] = (__bf16)((xv.y - mr.x) * mr.y * wv.y + bv.y);
    o[2] = (__bf16)((xv.z - mr.x) * mr.y * wv.z + bv.z);
    o[3] = (__bf16)((xv.w - mr.x) * mr.y * wv.w + bv.w);
    *(uint2*)(out + idx) = *(uint2*)o;
}

// ---------------------------------------------------------------- GEMM core 128x128, BK=64
// LDS: 2 k-slabs of [128 rows][32 cols]; 32 MFMA/wave per barrier pair.
__device__ __forceinline__ void gemm_core(
    const __bf16* __restrict__ A, const __bf16* __restrict__ BT,
    int K, int m0, int n0, __bf16* As, __bf16* Bs, floatx4 (&acc)[4][4])
{
    const int tid  = threadIdx.x;
    const int lane = tid & 63, wv = tid >> 6;
    const int quad = lane >> 4, l16 = lane & 15;
    const int wm = (wv >> 1) * 64, wn = (wv & 1) * 64;
    const int r0 = tid >> 2, c0 = (tid & 3) * 8;

    const __bf16* Ag = A  + (size_t)(m0 + r0) * K + c0;
    const __bf16* Bg = BT + (size_t)(n0 + r0) * K + c0;

    for (int kt = 0; kt < K; kt += 64) {
        __syncthreads();                 // prev iter's LDS reads done
#pragma unroll
        for (int s = 0; s < 2; ++s) {
            gload_lds16(Ag + kt + s * 32,                As + s * 4096 + tid * 8);
            gload_lds16(Ag + (size_t)64 * K + kt + s * 32, As + s * 4096 + 2048 + tid * 8);
            gload_lds16(Bg + kt + s * 32,                Bs + s * 4096 + tid * 8);
            gload_lds16(Bg + (size_t)64 * K + kt + s * 32, Bs + s * 4096 + 2048 + tid * 8);
        }
        __syncthreads();                 // drains vmcnt -> LDS filled
#pragma unroll
        for (int kk = 0; kk < 2; ++kk) {
            bf16x8 af[4], bfg[4];
#pragma unroll
            for (int i = 0; i < 4; ++i)
                af[i]  = *(const bf16x8*)(As + kk * 4096 + (wm + i * 16 + l16) * 32 + quad * 8);
#pragma unroll
            for (int i = 0; i < 4; ++i)
                bfg[i] = *(const bf16x8*)(Bs + kk * 4096 + (wn + i * 16 + l16) * 32 + quad * 8);
#pragma unroll
            for (int mi = 0; mi < 4; ++mi)
#pragma unroll
                for (int ni = 0; ni < 4; ++ni)
                    acc[mi][ni] = __builtin_amdgcn_mfma_f32_16x16x32_bf16(
                        af[mi], bfg[ni], acc[mi][ni], 0, 0, 0);
        }
    }
}

#define GEMM_PROLOGUE(KVAL)                                             \
    __shared__ __align__(16) __bf16 As[2 * 4096], Bs[2 * 4096];         \
    const int m0 = blockIdx.x * 128, n0 = blockIdx.y * 128;             \
    floatx4 acc[4][4];                                                  \
    { floatx4 z = {0.f, 0.f, 0.f, 0.f};                                 \
      for (int i = 0; i < 4; ++i) for (int j = 0; j < 4; ++j) acc[i][j] = z; } \
    gemm_core(A, BT, (KVAL), m0, n0, As, Bs, acc);                      \
    const int tid = threadIdx.x, lane = tid & 63, wv = tid >> 6;        \
    const int quad = lane >> 4, l16 = lane & 15;                        \
    const int wm = (wv >> 1) * 64, wn = (wv & 1) * 64;                  \
    (void)tid;

// QKV: q,k bf16 [B,NH,T,HD]; v transposed bf16 [B,NH,HD,T]; present fp32
__global__ __launch_bounds__(256) void gemm_qkv(
    const __bf16* __restrict__ A, const __bf16* __restrict__ BT,
    const float* __restrict__ bias, __bf16* __restrict__ qb,
    __bf16* __restrict__ kb, __bf16* __restrict__ vtb,
    float* __restrict__ present)
{
    GEMM_PROLOGUE(H_)
#pragma unroll
    for (int ni = 0; ni < 4; ++ni) {
        const int col = n0 + wn + ni * 16 + l16;
        const float bv = bias[col];
        const int which = col >> 10, c = col & 1023, hh = c >> 6, d = c & 63;
#pragma unroll
        for (int mi = 0; mi < 4; ++mi)
#pragma unroll
            for (int r = 0; r < 4; ++r) {
                const int row = m0 + wm + mi * 16 + quad * 4 + r;
                const int bb = row >> 11, t = row & 2047;
                const float v = acc[mi][ni][r] + bv;
                const size_t idx = (((size_t)bb * NH_ + hh) * T_ + t) * HD_ + d;
                if (which == 0)      qb[idx] = (__bf16)v;
                else if (which == 1) { kb[idx] = (__bf16)v; present[idx] = v; }
                else { vtb[(((size_t)bb * NH_ + hh) * HD_ + d) * T_ + t] = (__bf16)v;
                       present[(size_t)B_ * NH_ * T_ * HD_ + idx] = v; }
            }
    }
}

__global__ __launch_bounds__(256) void gemm_gelu(
    const __bf16* __restrict__ A, const __bf16* __restrict__ BT,
    const float* __restrict__ bias, __bf16* __restrict__ out)
{
    GEMM_PROLOGUE(H_)
#pragma unroll
    for (int ni = 0; ni < 4; ++ni) {
        const int col = n0 + wn + ni * 16 + l16;
        const float bv = bias[col];
#pragma unroll
        for (int mi = 0; mi < 4; ++mi)
#pragma unroll
            for (int r = 0; r < 4; ++r) {
                const int row = m0 + wm + mi * 16 + quad * 4 + r;
                const float v = acc[mi][ni][r] + bv;
                const float g = 0.5f * v *
                    (1.f + tanhf(0.7978845608028654f * (v + 0.044715f * v * v * v)));
                out[(size_t)row * (4 * H_) + col] = (__bf16)g;
            }
    }
}

// ---------------------------------------------------------------- GEMM 128x64 + resid, BK=64
__global__ __launch_bounds__(256) void gemm_resid_n64(
    const __bf16* __restrict__ A, const __bf16* __restrict__ BT,
    const float* __restrict__ bias, const float* __restrict__ resid,
    float* __restrict__ out, int K, int N)
{
    __shared__ __align__(16) __bf16 As[2 * 4096], Bs[2 * 2048];
    const int m0 = blockIdx.x * 128, n0 = blockIdx.y * 64;
    const int tid  = threadIdx.x;
    const int lane = tid & 63, wv = tid >> 6;
    const int quad = lane >> 4, l16 = lane & 15;
    const int wm = (wv >> 1) * 64, wn = (wv & 1) * 32;
    const int r0 = tid >> 2, c0 = (tid & 3) * 8;

    floatx4 acc[4][2];
    { floatx4 z = {0.f, 0.f, 0.f, 0.f};
#pragma unroll
      for (int i = 0; i < 4; ++i) { acc[i][0] = z; acc[i][1] = z; } }

    const __bf16* Ag = A  + (size_t)(m0 + r0) * K + c0;
    const __bf16* Bg = BT + (size_t)(n0 + r0) * K + c0;

    for (int kt = 0; kt < K; kt += 64) {
        __syncthreads();
#pragma unroll
        for (int s = 0; s < 2; ++s) {
            gload_lds16(Ag + kt + s * 32,                  As + s * 4096 + tid * 8);
            gload_lds16(Ag + (size_t)64 * K + kt + s * 32, As + s * 4096 + 2048 + tid * 8);
            gload_lds16(Bg + kt + s * 32,                  Bs + s * 2048 + tid * 8);
        }
        __syncthreads();
#pragma unroll
        for (int kk = 0; kk < 2; ++kk) {
            bf16x8 af[4], bfg[2];
#pragma unroll
            for (int i = 0; i < 4; ++i)
                af[i]  = *(const bf16x8*)(As + kk * 4096 + (wm + i * 16 + l16) * 32 + quad * 8);
#pragma unroll
            for (int i = 0; i < 2; ++i)
                bfg[i] = *(const bf16x8*)(Bs + kk * 2048 + (wn + i * 16 + l16) * 32 + quad * 8);
#pragma unroll
            for (int mi = 0; mi < 4; ++mi)
#pragma unroll
                for (int ni = 0; ni < 2; ++ni)
                    acc[mi][ni] = __builtin_amdgcn_mfma_f32_16x16x32_bf16(
                        af[mi], bfg[ni], acc[mi][ni], 0, 0, 0);
        }
    }

#pragma unroll
    for (int ni = 0; ni < 2; ++ni) {
        const int col = n0 + wn + ni * 16 + l16;
        const float bv = bias[col];
#pragma unroll
        for (int mi = 0; mi < 4; ++mi)
#pragma unroll
            for (int r = 0; r < 4; ++r) {
                const int row = m0 + wm + mi * 16 + quad * 4 + r;
                const size_t idx = (size_t)row * N + col;
                out[idx] = acc[mi][ni][r] + bv + resid[idx];
            }
    }
}

// ---------------------------------------------------------------- attention
// 64-row q-tiles, balanced pairs (sp, 31-sp) -> 33 k-iters/block, 512 blocks.
// grid (bh=32, pair=16): id%8 == bh%8 -> same-bh blocks share an XCD (K/V L2 reuse).
// Q/K/V staged via global_load_lds into 2-slab-stride-32 layout (conflict-free).
__global__ __launch_bounds__(256) void attn_kernel(
    const __bf16* __restrict__ qb, const __bf16* __restrict__ kb,
    const __bf16* __restrict__ vtb, __bf16* __restrict__ aout)
{
    const int bh = blockIdx.x, pr = blockIdx.y;
    const int bb = bh >> 4, hh = bh & 15;
    const __bf16* Q  = qb  + (size_t)bh * T_ * HD_;
    const __bf16* Kp = kb  + (size_t)bh * T_ * HD_;
    const __bf16* VT = vtb + (size_t)bh * HD_ * T_;
    __shared__ __align__(16) __bf16 Qs[2 * 2048], Ks[2 * 2048], Vs[2 * 2048];
    __shared__ __align__(16) __bf16 Ps[64 * PS_];

    const int tid = threadIdx.x, lane = tid & 63, wv = tid >> 6;
    const int quad = lane >> 4, l16 = lane & 15;
    const int sr = tid >> 2, sc = (tid & 3) * 8;   // staging row/col (64x32 per inst)

    for (int half = 0; half < 2; ++half) {
        const int sp = half ? (31 - pr) : pr;
        const int q0 = sp * 64;
        const int nkt = sp + 1;

        __syncthreads();   // prior half's LDS reads complete before restaging
#pragma unroll
        for (int s = 0; s < 2; ++s) {
            gload_lds16(Q  + (size_t)(q0 + sr) * HD_ + s * 32 + sc, Qs + s * 2048 + tid * 8);
            gload_lds16(Kp + (size_t)sr * HD_ + s * 32 + sc,        Ks + s * 2048 + tid * 8);
            gload_lds16(VT + (size_t)sr * T_  + s * 32 + sc,        Vs + s * 2048 + tid * 8);
        }

        float m_i[4], l_i[4];
        floatx4 Ov[4];
        { floatx4 z = {0.f, 0.f, 0.f, 0.f};
#pragma unroll
          for (int i = 0; i < 4; ++i) { Ov[i] = z; m_i[i] = -1e30f; l_i[i] = 0.f; } }

        for (int kt = 0; kt < nkt; ++kt) {
            __syncthreads();   // staging (vmcnt) drained

            // S = Q K^T : wave's 16 q-rows x 64 keys
            floatx4 sacc[4];
            { floatx4 z = {0.f, 0.f, 0.f, 0.f};
#pragma unroll
              for (int i = 0; i < 4; ++i) sacc[i] = z; }
#pragma unroll
            for (int kk = 0; kk < 2; ++kk) {
                const bf16x8 aq = *(const bf16x8*)(Qs + kk * 2048 + (wv * 16 + l16) * 32 + quad * 8);
#pragma unroll
                for (int ni = 0; ni < 4; ++ni) {
                    const bf16x8 bk = *(const bf16x8*)(Ks + kk * 2048 + (ni * 16 + l16) * 32 + quad * 8);
                    sacc[ni] = __builtin_amdgcn_mfma_f32_16x16x32_bf16(aq, bk, sacc[ni], 0, 0, 0);
                }
            }
            if (kt == sp) {    // diagonal tile: causal mask (local coords)
#pragma unroll
                for (int ni = 0; ni < 4; ++ni) {
                    const int keyL = ni * 16 + l16;
#pragma unroll
                    for (int r = 0; r < 4; ++r)
                        if (keyL > quad * 4 + r + wv * 16) sacc[ni][r] = -1e30f;
                }
            }
            // online softmax (4 rows/lane)
            float rmax[4], alpha[4], rsum[4];
#pragma unroll
            for (int r = 0; r < 4; ++r)
                rmax[r] = fmaxf(fmaxf(sacc[0][r], sacc[1][r]),
                                fmaxf(sacc[2][r], sacc[3][r]));
#pragma unroll
            for (int off = 1; off < 16; off <<= 1)
#pragma unroll
                for (int r = 0; r < 4; ++r)
                    rmax[r] = fmaxf(rmax[r], __shfl_xor(rmax[r], off, 64));
#pragma unroll
            for (int r = 0; r < 4; ++r) {
                const float mn = fmaxf(m_i[r], rmax[r]);
                alpha[r] = __expf(m_i[r] - mn);
                m_i[r] = mn;
                rsum[r] = 0.f;
            }
#pragma unroll
            for (int ni = 0; ni < 4; ++ni)
#pragma unroll
                for (int r = 0; r < 4; ++r) {
                    const float pe = __expf(sacc[ni][r] - m_i[r]);
                    sacc[ni][r] = pe;
                    rsum[r] += pe;
                }
#pragma unroll
            for (int off = 1; off < 16; off <<= 1)
#pragma unroll
                for (int r = 0; r < 4; ++r)
                    rsum[r] += __shfl_xor(rsum[r], off, 64);
#pragma unroll
            for (int r = 0; r < 4; ++r) {
                l_i[r] = l_i[r] * alpha[r] + rsum[r];
#pragma unroll
                for (int ni = 0; ni < 4; ++ni)
                    Ov[ni][r] *= alpha[r];
            }
            // P: C-layout -> A-layout via wave-private LDS rows (stride 72)
#pragma unroll
            for (int ni = 0; ni < 4; ++ni)
#pragma unroll
                for (int r = 0; r < 4; ++r)
                    Ps[(wv * 16 + quad * 4 + r) * PS_ + ni * 16 + l16] = (__bf16)sacc[ni][r];
            // O += P V
#pragma unroll
            for (int kk = 0; kk < 2; ++kk) {
                const bf16x8 ap = *(const bf16x8*)(Ps + (wv * 16 + l16) * PS_ + kk * 32 + quad * 8);
#pragma unroll
                for (int ni = 0; ni < 4; ++ni) {
                    const bf16x8 bv2 = *(const bf16x8*)(Vs + kk * 2048 + (ni * 16 + l16) * 32 + quad * 8);
                    Ov[ni] = __builtin_amdgcn_mfma_f32_16x16x32_bf16(ap, bv2, Ov[ni], 0, 0, 0);
                }
            }
            __syncthreads();   // all K/V/Q LDS reads done; safe to restage
            if (kt + 1 < nkt) {
                const int kn = kt + 1;
#pragma unroll
                for (int s = 0; s < 2; ++s) {
                    gload_lds16(Kp + (size_t)(kn * 64 + sr) * HD_ + s * 32 + sc, Ks + s * 2048 + tid * 8);
                    gload_lds16(VT + (size_t)sr * T_ + kn * 64 + s * 32 + sc,    Vs + s * 2048 + tid * 8);
                }
            }
        }
        // epilogue: aout[(b*T + t)][h*64 + d] = O / l
#pragma unroll
        for (int ni = 0; ni < 4; ++ni)
#pragma unroll
            for (int r = 0; r < 4; ++r) {
                const int t = q0 + wv * 16 + quad * 4 + r;
                aout[((size_t)(bb * T_ + t)) * H_ + hh * HD_ + ni * 16 + l16] =
                    (__bf16)(Ov[ni][r] / l_i[r]);
            }
    }
}

// ---------------------------------------------------------------- launch
extern "C" void kernel_launch(void* const* d_in, const int* in_sizes, int n_in,
                              void* d_out, int out_size, void* d_ws, size_t ws_size,
                              hipStream_t stream)
{
    (void)in_sizes; (void)n_in; (void)out_size; (void)ws_size;
    const float* x       = (const float*)d_in[0];
    const float* w_attn  = (const float*)d_in[1];
    const float* b_attn  = (const float*)d_in[2];
    const float* w_aproj = (const float*)d_in[3];
    const float* b_aproj = (const float*)d_in[4];
    const float* ln1_w   = (const float*)d_in[5];
    const float* ln1_b   = (const float*)d_in[6];
    const float* ln2_w   = (const float*)d_in[7];
    const float* ln2_b   = (const float*)d_in[8];
    const float* w_fc    = (const float*)d_in[9];
    const float* b_fc    = (const float*)d_in[10];
    const float* w_mproj = (const float*)d_in[11];
    const float* b_mproj = (const float*)d_in[12];
    float* out = (float*)d_out;
    float* present = out + (size_t)M_ * H_;

    char* wp = (char*)d_ws;
    auto alloc = [&](size_t bytes) {
        void* p = (void*)wp; wp += (bytes + 255) & ~(size_t)255; return p;
    };
    __bf16* A1       = (__bf16*)alloc((size_t)M_ * H_ * 2);
    __bf16* A2       = (__bf16*)alloc((size_t)M_ * H_ * 2);
    __bf16* WattnT   = (__bf16*)alloc((size_t)3 * H_ * H_ * 2);
    __bf16* WaprojT  = (__bf16*)alloc((size_t)H_ * H_ * 2);
    __bf16* WfcT     = (__bf16*)alloc((size_t)4 * H_ * H_ * 2);
    __bf16* WmprojT  = (__bf16*)alloc((size_t)4 * H_ * H_ * 2);
    __bf16* qb       = (__bf16*)alloc((size_t)M_ * H_ * 2);
    __bf16* kb       = (__bf16*)alloc((size_t)M_ * H_ * 2);
    __bf16* vtb      = (__bf16*)alloc((size_t)M_ * H_ * 2);
    __bf16* attn_out = (__bf16*)alloc((size_t)M_ * H_ * 2);
    float*  x2       = (float*) alloc((size_t)M_ * H_ * 4);
    __bf16* Hbuf     = (__bf16*)alloc((size_t)M_ * 4 * H_ * 2);
    float2* gn_part  = (float2*)alloc(64 * 16 * sizeof(float2));
    float2* gn_stats = (float2*)alloc(64 * sizeof(float2));

    transpose_bf16<<<dim3(H_/32, 3*H_/32), 256, 0, stream>>>(w_attn,  WattnT,  H_,   3*H_);
    transpose_bf16<<<dim3(H_/32, H_/32),   256, 0, stream>>>(w_aproj, WaprojT, H_,   H_);
    transpose_bf16<<<dim3(H_/32, 4*H_/32), 256, 0, stream>>>(w_fc,    WfcT,    H_,   4*H_);
    transpose_bf16<<<dim3(4*H_/32, H_/32), 256, 0, stream>>>(w_mproj, WmprojT, 4*H_, H_);

    gn_partial <<<dim3(64, 16), 256, 0, stream>>>(x, gn_part);
    gn_finalize<<<1, 64, 0, stream>>>(gn_part, gn_stats);
    gn_apply   <<<M_*H_/1024, 256, 0, stream>>>(x, gn_stats, ln1_w, ln1_b, A1);

    gemm_qkv<<<dim3(M_/128, 3*H_/128), 256, 0, stream>>>(A1, WattnT, b_attn,
                                                         qb, kb, vtb, present);
    attn_kernel<<<dim3(32, 16), 256, 0, stream>>>(qb, kb, vtb, attn_out);
    gemm_resid_n64<<<dim3(M_/128, H_/64), 256, 0, stream>>>(attn_out, WaprojT, b_aproj,
                                                            x, x2, H_, H_);

    gn_partial <<<dim3(64, 16), 256, 0, stream>>>(x2, gn_part);
    gn_finalize<<<1, 64, 0, stream>>>(gn_part, gn_stats);
    gn_apply   <<<M_*H_/1024, 256, 0, stream>>>(x2, gn_stats, ln2_w, ln2_b, A2);

    gemm_gelu<<<dim3(M_/128, 4*H_/128), 256, 0, stream>>>(A2, WfcT, b_fc, Hbuf);
    gemm_resid_n64<<<dim3(M_/128, H_/64), 256, 0, stream>>>(Hbuf, WmprojT, b_mproj,
                                                            x2, out, 4*H_, H_);
}